// Round 7
// baseline (215.671 us; speedup 1.0000x reference)
//
#include <hip/hip_runtime.h>
#include <hip/hip_cooperative_groups.h>

namespace cg = cooperative_groups;

typedef __attribute__((ext_vector_type(8))) short short8;
typedef __attribute__((ext_vector_type(4))) float f32x4;
typedef __attribute__((ext_vector_type(2))) unsigned int u32x2;
typedef __attribute__((ext_vector_type(4))) unsigned int u32x4;

#define THRE 4.0f

#define GLOAD_LDS16(g, l) \
    __builtin_amdgcn_global_load_lds((const __attribute__((address_space(1))) void*)(g), \
                                     (__attribute__((address_space(3))) void*)(l), 16, 0, 0)

__device__ __forceinline__ float spikef(float x) {
    return floorf(fminf(fmaxf(x, 0.0f), THRE) + 0.5f);
}
__device__ __forceinline__ unsigned short f2bf(float f) {   // truncate; exact for small ints
    return (unsigned short)(__builtin_bit_cast(unsigned int, f) >> 16);
}

// ================= shared building blocks =================

// GEMM tile: C[.,N] = A @ B^T (+bias), BM=MT*32, BN=NT*32, BK=32, 256 threads.
template<int MT, int NT, bool BIAS, bool BNSTATS>
__device__ void gemm_phase(short* SM, const short* __restrict__ A, const short* __restrict__ B,
                           const float* __restrict__ bias, float* __restrict__ C,
                           float* __restrict__ psum, float* __restrict__ psq,
                           int m0, int n0, int K, int N, int stripe) {
    constexpr int BM = MT * 32, BN = NT * 32;
    short* As = SM;
    short* Bs = SM + BM * 32;
    const int tid  = threadIdx.x;
    const int lane = tid & 63, wv = tid >> 6;
    const int wy = wv >> 1, wx = wv & 1;
    const int quad = lane >> 4, l16 = lane & 15;

    f32x4 acc[MT][NT];
    #pragma unroll
    for (int i = 0; i < MT; ++i)
        #pragma unroll
        for (int j = 0; j < NT; ++j)
            #pragma unroll
            for (int r = 0; r < 4; ++r) acc[i][j][r] = 0.f;

    constexpr int LA = 2 * MT, LB = 2 * NT;
    const short* gA[(LA + 3) / 4]; short* lA[(LA + 3) / 4]; int nA = 0;
    #pragma unroll
    for (int L0 = 0; L0 < LA; L0 += 4) {
        int L = L0 + wv;
        if (L < LA) {
            int c = L * 64 + lane;
            gA[nA] = A + (size_t)(m0 + (c >> 2)) * K + (c & 3) * 8;
            lA[nA] = &As[L * 512];
            ++nA;
        }
    }
    const short* gB[(LB + 3) / 4]; short* lB[(LB + 3) / 4]; int nB = 0;
    #pragma unroll
    for (int L0 = 0; L0 < LB; L0 += 4) {
        int L = L0 + wv;
        if (L < LB) {
            int c = L * 64 + lane;
            gB[nB] = B + (size_t)(n0 + (c >> 2)) * K + (c & 3) * 8;
            lB[nB] = &Bs[L * 512];
            ++nB;
        }
    }

    for (int k0 = 0; k0 < K; k0 += 32) {
        __syncthreads();
        for (int i = 0; i < nA; ++i) GLOAD_LDS16(gA[i] + k0, lA[i]);
        for (int i = 0; i < nB; ++i) GLOAD_LDS16(gB[i] + k0, lB[i]);
        __syncthreads();
        short8 aF[MT], bF[NT];
        #pragma unroll
        for (int mt = 0; mt < MT; ++mt)
            aF[mt] = *(const short8*)&As[(wy * MT * 16 + mt * 16 + l16) * 32 + quad * 8];
        #pragma unroll
        for (int nt = 0; nt < NT; ++nt)
            bF[nt] = *(const short8*)&Bs[(wx * NT * 16 + nt * 16 + l16) * 32 + quad * 8];
        #pragma unroll
        for (int mt = 0; mt < MT; ++mt)
            #pragma unroll
            for (int nt = 0; nt < NT; ++nt)
                acc[mt][nt] = __builtin_amdgcn_mfma_f32_16x16x32_bf16(aF[mt], bF[nt], acc[mt][nt], 0, 0, 0);
    }

    float bs[NT];
    #pragma unroll
    for (int nt = 0; nt < NT; ++nt) bs[nt] = BIAS ? bias[n0 + wx * NT * 16 + nt * 16 + l16] : 0.f;
    #pragma unroll
    for (int mt = 0; mt < MT; ++mt)
        #pragma unroll
        for (int r = 0; r < 4; ++r) {
            int row = m0 + wy * MT * 16 + mt * 16 + quad * 4 + r;
            float* Cr = C + (size_t)row * N + n0 + wx * NT * 16 + l16;
            #pragma unroll
            for (int nt = 0; nt < NT; ++nt) Cr[nt * 16] = acc[mt][nt][r] + bs[nt];
        }

    if (BNSTATS) {
        __syncthreads();
        float* PS = (float*)SM;                // [8][BN] floats
        float* PQ = (float*)(SM + 2 * 8 * BN); // byte offset 4*8*BN
        #pragma unroll
        for (int nt = 0; nt < NT; ++nt) {
            float s = 0.f, q = 0.f;
            #pragma unroll
            for (int mt = 0; mt < MT; ++mt)
                #pragma unroll
                for (int r = 0; r < 4; ++r) {
                    float v = acc[mt][nt][r];
                    s += v;
                    q = fmaf(v, v, q);
                }
            PS[(wy * 4 + quad) * BN + wx * NT * 16 + nt * 16 + l16] = s;
            PQ[(wy * 4 + quad) * BN + wx * NT * 16 + nt * 16 + l16] = q;
        }
        __syncthreads();
        if (tid < BN) {
            float s = 0.f, q = 0.f;
            #pragma unroll
            for (int i = 0; i < 8; ++i) { s += PS[i * BN + tid]; q += PQ[i * BN + tid]; }
            psum[stripe * 1536 + n0 + tid] = s;
            psq [stripe * 1536 + n0 + tid] = q;
        }
    }
}

// stats finalize for one 64-channel slice into sa/sb (leading barrier protects reuse)
__device__ void bn_slice_stats(const float* __restrict__ psum, const float* __restrict__ psq,
                               const float* __restrict__ gamma, const float* __restrict__ beta,
                               int c0, float* sa, float* sb) {
    const int tid = threadIdx.x;
    __syncthreads();
    if (tid < 64) {
        const int c = c0 + tid;
        double s = 0.0, q = 0.0;
        for (int st = 0; st < 32; ++st) { s += (double)psum[st * 1536 + c]; q += (double)psq[st * 1536 + c]; }
        const double mu  = s / 4096.0;
        const double var = q / 4096.0 - mu * mu;
        const float a = (float)((double)gamma[c] / sqrt(var + 1e-5));
        sa[tid] = a;
        sb[tid] = fmaf(-(float)mu, a, beta[c]);
    }
    __syncthreads();
}

// one attention unit (64 q-rows of one (b,h)); u in [0,512)
__device__ void attn_unit(short* SM, const short* __restrict__ qp, const short* __restrict__ kp,
                          const short* __restrict__ vt, short* __restrict__ sout, int u) {
    short* Qs = SM;                          // 64*72
    short* Ks = SM + 4608;                   // 128*72
    short* Vs = SM + 13824;                  // 64*136
    unsigned int* SC = (unsigned int*)(SM + 22528);
    const int tid = threadIdx.x;
    const int lane = tid & 63, wv3 = tid >> 6;
    const int quad = lane >> 4, l16 = lane & 15;
    const int b = u >> 7, h = (u >> 4) & 7;
    const int n0 = (u & 15) * 64;
    const size_t bh = (size_t)b * 8 + h;

    {
        const int row = tid >> 2, c0 = (tid & 3) * 16;
        const short* g = qp + (bh * 1024 + n0 + row) * 64 + c0;
        *(short8*)&Qs[row * 72 + c0]     = *(const short8*)(g);
        *(short8*)&Qs[row * 72 + c0 + 8] = *(const short8*)(g + 8);
    }
    __syncthreads();
    short8 qf[4][2];
    #pragma unroll
    for (int mt = 0; mt < 4; ++mt)
        #pragma unroll
        for (int kq = 0; kq < 2; ++kq)
            qf[mt][kq] = *(const short8*)&Qs[(mt * 16 + l16) * 72 + kq * 32 + quad * 8];

    f32x4 of[4][4];
    #pragma unroll
    for (int et = 0; et < 4; ++et)
        #pragma unroll
        for (int mt = 0; mt < 4; ++mt)
            #pragma unroll
            for (int r = 0; r < 4; ++r) of[et][mt][r] = 0.f;

    const int krow = tid >> 1, kc0 = (tid & 1) * 32;
    const int ve = tid >> 2,  vc0 = (tid & 3) * 32;
    unsigned int* buf0 = SC + wv3 * 256;
    unsigned int* buf1 = SC + 1024 + wv3 * 256;
    const int s0 = (l16 + 16 * ((2 * quad) & 3)) * 4 + (quad >> 1) * 2;
    const int s1 = (l16 + 16 * ((2 * quad + 1) & 3)) * 4 + (quad >> 1) * 2;

    for (int j0 = 0; j0 < 1024; j0 += 128) {
        __syncthreads();
        {
            const short* g = kp + (bh * 1024 + j0 + krow) * 64 + kc0;
            #pragma unroll
            for (int i = 0; i < 4; ++i)
                *(short8*)&Ks[krow * 72 + kc0 + i * 8] = *(const short8*)(g + i * 8);
            const short* gv = vt + (bh * 64 + ve) * 1024 + j0 + vc0;
            #pragma unroll
            for (int i = 0; i < 4; ++i)
                *(short8*)&Vs[ve * 136 + vc0 + i * 8] = *(const short8*)(gv + i * 8);
        }
        __syncthreads();

        f32x4 sacc[4][2];
        #pragma unroll
        for (int mt = 0; mt < 4; ++mt)
            #pragma unroll
            for (int nt = 0; nt < 2; ++nt)
                #pragma unroll
                for (int r = 0; r < 4; ++r) sacc[mt][nt][r] = 0.f;
        #pragma unroll
        for (int kq = 0; kq < 2; ++kq) {
            short8 kf0 = *(const short8*)&Ks[(wv3 * 32 +      l16) * 72 + kq * 32 + quad * 8];
            short8 kf1 = *(const short8*)&Ks[(wv3 * 32 + 16 + l16) * 72 + kq * 32 + quad * 8];
            #pragma unroll
            for (int mt = 0; mt < 4; ++mt) {
                sacc[mt][0] = __builtin_amdgcn_mfma_f32_16x16x32_bf16(kf0, qf[mt][kq], sacc[mt][0], 0, 0, 0);
                sacc[mt][1] = __builtin_amdgcn_mfma_f32_16x16x32_bf16(kf1, qf[mt][kq], sacc[mt][1], 0, 0, 0);
            }
        }
        short8 aS[4];
        #pragma unroll
        for (int mt = 0; mt < 4; ++mt) {
            unsigned int pk[4];
            #pragma unroll
            for (int nt = 0; nt < 2; ++nt)
                #pragma unroll
                for (int rp = 0; rp < 2; ++rp) {
                    unsigned int lo = f2bf(spikef(sacc[mt][nt][2 * rp]));
                    unsigned int hi = f2bf(spikef(sacc[mt][nt][2 * rp + 1]));
                    pk[nt * 2 + rp] = lo | (hi << 16);
                }
            unsigned int* buf = (mt & 1) ? buf1 : buf0;
            u32x2 wa; wa.x = pk[0]; wa.y = pk[1];
            u32x2 wb; wb.x = pk[2]; wb.y = pk[3];
            *(u32x2*)&buf[lane * 4]     = wa;
            *(u32x2*)&buf[lane * 4 + 2] = wb;
            if (mt > 0) {
                unsigned int* pb = (mt & 1) ? buf0 : buf1;
                u32x2 lo = *(const u32x2*)&pb[s0];
                u32x2 hi = *(const u32x2*)&pb[s1];
                u32x4 t; t.x = lo.x; t.y = lo.y; t.z = hi.x; t.w = hi.y;
                aS[mt - 1] = __builtin_bit_cast(short8, t);
            }
        }
        {
            u32x2 lo = *(const u32x2*)&buf1[s0];
            u32x2 hi = *(const u32x2*)&buf1[s1];
            u32x4 t; t.x = lo.x; t.y = lo.y; t.z = hi.x; t.w = hi.y;
            aS[3] = __builtin_bit_cast(short8, t);
        }

        #pragma unroll
        for (int et = 0; et < 4; ++et) {
            short8 bV = *(const short8*)&Vs[(et * 16 + l16) * 136 + wv3 * 32 + quad * 8];
            #pragma unroll
            for (int mt = 0; mt < 4; ++mt)
                of[et][mt] = __builtin_amdgcn_mfma_f32_16x16x32_bf16(aS[mt], bV, of[et][mt], 0, 0, 0);
        }
    }

    __syncthreads();
    float* P2 = (float*)Ks;
    float* P3 = (float*)Vs;
    if (wv3 == 2 || wv3 == 3) {
        float* P = (wv3 == 2) ? P2 : P3;
        #pragma unroll
        for (int et = 0; et < 4; ++et)
            #pragma unroll
            for (int mt = 0; mt < 4; ++mt)
                *(f32x4*)&P[(et * 16 + l16) * 68 + mt * 16 + quad * 4] = of[et][mt];
    }
    __syncthreads();
    if (wv3 == 0 || wv3 == 1) {
        float* P = (wv3 == 0) ? P2 : P3;
        #pragma unroll
        for (int et = 0; et < 4; ++et)
            #pragma unroll
            for (int mt = 0; mt < 4; ++mt) {
                f32x4 t = *(const f32x4*)&P[(et * 16 + l16) * 68 + mt * 16 + quad * 4];
                #pragma unroll
                for (int r = 0; r < 4; ++r) of[et][mt][r] += t[r];
            }
    }
    __syncthreads();
    if (wv3 == 1) {
        #pragma unroll
        for (int et = 0; et < 4; ++et)
            #pragma unroll
            for (int mt = 0; mt < 4; ++mt)
                *(f32x4*)&P2[(et * 16 + l16) * 68 + mt * 16 + quad * 4] = of[et][mt];
    }
    __syncthreads();
    if (wv3 == 0) {
        #pragma unroll
        for (int et = 0; et < 4; ++et)
            #pragma unroll
            for (int mt = 0; mt < 4; ++mt) {
                f32x4 t = *(const f32x4*)&P2[(et * 16 + l16) * 68 + mt * 16 + quad * 4];
                #pragma unroll
                for (int r = 0; r < 4; ++r) {
                    size_t orow = (size_t)b * 1024 + n0 + mt * 16 + quad * 4 + r;
                    sout[orow * 512 + h * 64 + et * 16 + l16] =
                        (short)f2bf(spikef((of[et][mt][r] + t[r]) * 0.125f));
                }
            }
    }
    __syncthreads();   // protect SM reuse by next unit / next phase
}

// ================= cooperative mega-kernel (flexible grid) =================
__global__ __launch_bounds__(256, 2) void k_mega(
        const float* __restrict__ x, const float* __restrict__ Wq,
        const float* __restrict__ gamma, const float* __restrict__ beta,
        const float* __restrict__ Wp, const float* __restrict__ bp,
        short* __restrict__ xs2, short* __restrict__ Wqd, short* __restrict__ Wpd,
        float* __restrict__ qkv, short* __restrict__ qp, short* __restrict__ kp,
        short* __restrict__ vt, float* __restrict__ psum, float* __restrict__ psq,
        short* __restrict__ sout, float* __restrict__ out, int probe) {
    if (probe) return;
    __shared__ __align__(16) short SM[26624];   // 53248 B
    cg::grid_group grid = cg::this_grid();
    const int tid = threadIdx.x;
    const int nb = gridDim.x;

    // ---- P0: prep ----
    {
        const int T = nb * 256;
        const int base = blockIdx.x * 256 + tid;
        for (int i = base; i < 2097152; i += T) {
            int r = i >> 9, c = i & 511;
            short bfv = (short)f2bf(spikef(x[i]));
            xs2[(size_t)r * 1024 + c]       = bfv;
            xs2[(size_t)r * 1024 + 512 + c] = bfv;
        }
        for (int j = base; j < 786432; j += T) {
            int r = j >> 9, c = j & 511;
            float f = Wq[j];
            unsigned u2 = __builtin_bit_cast(unsigned int, f);
            float fhi = __builtin_bit_cast(float, u2 & 0xffff0000u);
            Wqd[(size_t)r * 1024 + c]       = (short)(u2 >> 16);
            Wqd[(size_t)r * 1024 + 512 + c] = (short)f2bf(f - fhi);
        }
        for (int j = base; j < 262144; j += T)
            Wpd[j] = (short)(__builtin_bit_cast(unsigned int, Wp[j]) >> 16);
    }
    grid.sync();

    // ---- P1: qkv GEMM + BN partial stats (512 tiles) ----
    for (int u = blockIdx.x; u < 512; u += nb)
        gemm_phase<4, 3, false, true>(SM, xs2, Wqd, nullptr, qkv, psum, psq,
                                      (u >> 4) * 128, (u & 15) * 96, 1024, 1536, u >> 4);
    grid.sync();

    // ---- P2: BN finalize + spike + pack (512 q/k units + 512 v units) ----
    for (int u = blockIdx.x; u < 512; u += nb) {
        float* sa = (float*)SM;
        float* sb = sa + 64;
        short* tile = SM + 256;
        {   // q/k unit
            const int s = u >> 5, rg = u & 31;
            const int c0 = s * 64, r0 = rg * 128;
            bn_slice_stats(psum, psq, gamma, beta, c0, sa, sb);
            const int ch = tid & 63, rq = tid >> 6;
            const float A = sa[ch], Bb = sb[ch];
            const int b = r0 >> 10, n0b = r0 & 1023;
            short* base = (s < 8 ? qp : kp) + (((size_t)b * 8 + (s & 7)) * 1024 + n0b) * 64;
            for (int i = rq; i < 128; i += 4) {
                float v = qkv[(size_t)(r0 + i) * 1536 + c0 + ch];
                base[i * 64 + ch] = (short)f2bf(spikef(fmaf(v, A, Bb)));
            }
        }
        {   // v unit
            const int h = u >> 6, rg = u & 63;
            const int c0 = 1024 + h * 64, r0 = rg * 64;
            bn_slice_stats(psum, psq, gamma, beta, c0, sa, sb);
            const int ch = tid & 63, rq = tid >> 6;
            const float A = sa[ch], Bb = sb[ch];
            const int b = r0 >> 10, n0b = r0 & 1023;
            for (int i = rq; i < 64; i += 4) {
                float v = qkv[(size_t)(r0 + i) * 1536 + c0 + ch];
                tile[ch * 72 + i] = (short)f2bf(spikef(fmaf(v, A, Bb)));
            }
            __syncthreads();
            const int e = tid >> 2, j0 = (tid & 3) * 16;
            short* vbase = vt + (((size_t)b * 8 + h) * 64 + e) * 1024 + n0b;
            *(short8*)&vbase[j0]     = *(const short8*)&tile[e * 72 + j0];
            *(short8*)&vbase[j0 + 8] = *(const short8*)&tile[e * 72 + j0 + 8];
        }
    }
    grid.sync();

    // ---- P3: attention (512 units) ----
    for (int u = blockIdx.x; u < 512; u += nb)
        attn_unit(SM, qp, kp, vt, sout, u);
    grid.sync();

    // ---- P4: proj GEMM (512 tiles) ----
    for (int u = blockIdx.x; u < 512; u += nb)
        gemm_phase<1, 4, true, false>(SM, sout, Wpd, bp, out, nullptr, nullptr,
                                      (u >> 2) * 32, (u & 3) * 128, 512, 512, 0);
}

// ================= fallback kernels (round-5, proven) =================
__global__ void k_prep(const float* __restrict__ x,
                       const float* __restrict__ Wq, const float* __restrict__ Wp,
                       short* __restrict__ xs2, short* __restrict__ Wqd, short* __restrict__ Wpd) {
    int i = blockIdx.x * 256 + threadIdx.x;
    if (i < 2097152) {
        int r = i >> 9, c = i & 511;
        short b = (short)f2bf(spikef(x[i]));
        xs2[(size_t)r * 1024 + c]       = b;
        xs2[(size_t)r * 1024 + 512 + c] = b;
    } else if (i < 2883584) {
        int j = i - 2097152;
        int r = j >> 9, c = j & 511;
        float f = Wq[j];
        unsigned u = __builtin_bit_cast(unsigned int, f);
        float fhi = __builtin_bit_cast(float, u & 0xffff0000u);
        Wqd[(size_t)r * 1024 + c]       = (short)(u >> 16);
        Wqd[(size_t)r * 1024 + 512 + c] = (short)f2bf(f - fhi);
    } else {
        int j = i - 2883584;
        Wpd[j] = (short)(__builtin_bit_cast(unsigned int, Wp[j]) >> 16);
    }
}

template<int MT, int NT, bool BIAS, bool BNSTATS>
__global__ __launch_bounds__(256) void k_gemm(const short* __restrict__ A, const short* __restrict__ B,
                                              const float* __restrict__ bias, float* __restrict__ C,
                                              float* __restrict__ psum, float* __restrict__ psq,
                                              int K, int N) {
    __shared__ __align__(16) short SM[(MT + NT) * 32 * 32];
    gemm_phase<MT, NT, BIAS, BNSTATS>(SM, A, B, bias, C, psum, psq,
                                      blockIdx.y * MT * 32, blockIdx.x * NT * 32, K, N, blockIdx.y);
}

__global__ __launch_bounds__(256) void k_bn_spike(const float* __restrict__ qkv,
                           const float* __restrict__ psum, const float* __restrict__ psq,
                           const float* __restrict__ gamma, const float* __restrict__ beta,
                           short* __restrict__ qp, short* __restrict__ kp, short* __restrict__ vt) {
    __shared__ float sa[64], sb[64];
    __shared__ short tile[64 * 72];
    const int tid = threadIdx.x;
    const int slice = blockIdx.x;
    const int c0 = slice * 64;
    const int r0 = blockIdx.y * 256;
    const int b = r0 >> 10, nb = r0 & 1023;

    if (tid < 64) {
        const int c = c0 + tid;
        double s = 0.0, q = 0.0;
        for (int st = 0; st < 32; ++st) { s += (double)psum[st * 1536 + c]; q += (double)psq[st * 1536 + c]; }
        const double mu  = s / 4096.0;
        const double var = q / 4096.0 - mu * mu;
        const float a = (float)((double)gamma[c] / sqrt(var + 1e-5));
        sa[tid] = a;
        sb[tid] = fmaf(-(float)mu, a, beta[c]);
    }
    __syncthreads();

    const int ch = tid & 63, rq = tid >> 6;
    const float A = sa[ch], Bsh = sb[ch];

    if (slice < 16) {
        const int h = slice & 7;
        short* base = (slice < 8 ? qp : kp) + (((size_t)b * 8 + h) * 1024 + nb) * 64;
        for (int i = rq; i < 256; i += 4) {
            float v = qkv[(size_t)(r0 + i) * 1536 + c0 + ch];
            base[(size_t)i * 64 + ch] = (short)f2bf(spikef(fmaf(v, A, Bsh)));
        }
    } else {
        const int h = slice - 16;
        const int e = tid >> 2, j0 = (tid & 3) * 16;
        short* vbase = vt + (((size_t)b * 8 + h) * 64 + e) * 1024 + nb;
        for (int rb = 0; rb < 4; ++rb) {
            __syncthreads();
            for (int i = rq; i < 64; i += 4) {
                float v = qkv[(size_t)(r0 + rb * 64 + i) * 1536 + c0 + ch];
                tile[ch * 72 + i] = (short)f2bf(spikef(fmaf(v, A, Bsh)));
            }
            __syncthreads();
            *(short8*)&vbase[rb * 64 + j0]     = *(const short8*)&tile[e * 72 + j0];
            *(short8*)&vbase[rb * 64 + j0 + 8] = *(const short8*)&tile[e * 72 + j0 + 8];
        }
    }
}

__global__ __launch_bounds__(256) void k_attn(const short* __restrict__ qp,
                                              const short* __restrict__ kp,
                                              const short* __restrict__ vt,
                                              short* __restrict__ sout) {
    __shared__ __align__(16) short SM[26624];
    attn_unit(SM, qp, kp, vt, sout, blockIdx.x);
}

// ================= load-time cooperative probe =================
static int g_coop_grid = 0;

namespace {
struct CoopProbe {
    CoopProbe() {
        hipStream_t s;
        if (hipStreamCreate(&s) != hipSuccess) { (void)hipGetLastError(); return; }
        void* np = nullptr;
        int probe_one = 1;
        void* args[18];
        for (int i = 0; i < 17; ++i) args[i] = &np;
        args[17] = &probe_one;
        const int grids[2] = {512, 256};
        for (int gi = 0; gi < 2 && !g_coop_grid; ++gi) {
            int g = grids[gi];
            // (a) direct launch
            hipError_t e = hipLaunchCooperativeKernel((const void*)k_mega, dim3(g), dim3(256), args, 0, s);
            if (e != hipSuccess || hipStreamSynchronize(s) != hipSuccess) { (void)hipGetLastError(); continue; }
            // (b) capture + instantiate + replay
            hipGraph_t graph = nullptr;
            if (hipStreamBeginCapture(s, hipStreamCaptureModeThreadLocal) != hipSuccess) { (void)hipGetLastError(); continue; }
            e = hipLaunchCooperativeKernel((const void*)k_mega, dim3(g), dim3(256), args, 0, s);
            hipError_t e2 = hipStreamEndCapture(s, &graph);
            if (e == hipSuccess && e2 == hipSuccess && graph) {
                hipGraphExec_t ge = nullptr;
                if (hipGraphInstantiate(&ge, graph, nullptr, nullptr, 0) == hipSuccess) {
                    if (hipGraphLaunch(ge, s) == hipSuccess && hipStreamSynchronize(s) == hipSuccess)
                        g_coop_grid = g;
                    hipGraphExecDestroy(ge);
                }
            }
            if (graph) hipGraphDestroy(graph);
            (void)hipGetLastError();
        }
        hipStreamDestroy(s);
        (void)hipGetLastError();
    }
};
static CoopProbe g_probe_obj;
}

extern "C" void kernel_launch(void* const* d_in, const int* in_sizes, int n_in,
                              void* d_out, int out_size, void* d_ws, size_t ws_size,
                              hipStream_t stream) {
    const float* x     = (const float*)d_in[0];
    const float* Wqkv  = (const float*)d_in[1];
    const float* gamma = (const float*)d_in[2];
    const float* beta  = (const float*)d_in[3];
    const float* Wproj = (const float*)d_in[4];
    const float* bproj = (const float*)d_in[5];
    float* out = (float*)d_out;

    char* w = (char*)d_ws;
    short* xs2  = (short*)(w);
    short* Wqd  = (short*)(w + 8388608);
    short* Wpd  = (short*)(w + 11534336);
    float* qkv  = (float*)(w + 12582912);
    short* qp   = (short*)(w + 37748736);
    short* kp   = (short*)(w + 41943040);
    short* vt   = (short*)(w + 46137344);
    float* psum = (float*)(w + 50331648);
    float* psq  = (float*)(w + 50528256);
    short* sout = (short*)(w + 50724864);

    if (g_coop_grid > 0) {
        int probe = 0;
        void* args[18] = {
            (void*)&x, (void*)&Wqkv, (void*)&gamma, (void*)&beta, (void*)&Wproj, (void*)&bproj,
            (void*)&xs2, (void*)&Wqd, (void*)&Wpd, (void*)&qkv, (void*)&qp, (void*)&kp,
            (void*)&vt, (void*)&psum, (void*)&psq, (void*)&sout, (void*)&out, (void*)&probe
        };
        hipLaunchCooperativeKernel((const void*)k_mega, dim3(g_coop_grid), dim3(256), args, 0, stream);
    } else {
        k_prep<<<12288, 256, 0, stream>>>(x, Wqkv, Wproj, xs2, Wqd, Wpd);
        k_gemm<4, 3, false, true><<<dim3(16, 32), 256, 0, stream>>>(xs2, Wqd, nullptr, qkv, psum, psq, 1024, 1536);
        k_bn_spike<<<dim3(24, 16), 256, 0, stream>>>(qkv, psum, psq, gamma, beta, qp, kp, vt);
        k_attn<<<dim3(512), 256, 0, stream>>>(qp, kp, vt, sout);
        k_gemm<1, 4, true, false><<<dim3(4, 128), 256, 0, stream>>>(sout, Wpd, bproj, out, nullptr, nullptr, 512, 512);
    }
}

// Round 8
// 143.169 us; speedup vs baseline: 1.5064x; 1.5064x over previous
//
#include <hip/hip_runtime.h>

typedef __attribute__((ext_vector_type(8))) short short8;
typedef __attribute__((ext_vector_type(4))) float f32x4;
typedef __attribute__((ext_vector_type(2))) unsigned int u32x2;
typedef __attribute__((ext_vector_type(4))) unsigned int u32x4;

#define THRE 4.0f

#define GLOAD_LDS16(g, l) \
    __builtin_amdgcn_global_load_lds((const __attribute__((address_space(1))) void*)(g), \
                                     (__attribute__((address_space(3))) void*)(l), 16, 0, 0)

__device__ __forceinline__ float spikef(float x) {
    return floorf(fminf(fmaxf(x, 0.0f), THRE) + 0.5f);
}
__device__ __forceinline__ unsigned short f2bf(float f) {   // truncate; exact for small ints
    return (unsigned short)(__builtin_bit_cast(unsigned int, f) >> 16);
}

// ---------- fused prep: spike(x)->bf16 dup halves; Wqkv -> bf16 hi|lo; Wproj -> hi ----------
__global__ void k_prep(const float* __restrict__ x,
                       const float* __restrict__ Wq, const float* __restrict__ Wp,
                       short* __restrict__ xs2, short* __restrict__ Wqd, short* __restrict__ Wpd) {
    int i = blockIdx.x * 256 + threadIdx.x;             // 12288 blocks
    if (i < 2097152) {                                   // x: 4096*512
        int r = i >> 9, c = i & 511;
        short b = (short)f2bf(spikef(x[i]));
        xs2[(size_t)r * 1024 + c]       = b;
        xs2[(size_t)r * 1024 + 512 + c] = b;
    } else if (i < 2883584) {                            // Wqkv: 1536*512, hi|lo [r][2K]
        int j = i - 2097152;
        int r = j >> 9, c = j & 511;
        float f = Wq[j];
        unsigned u = __builtin_bit_cast(unsigned int, f);
        float fhi = __builtin_bit_cast(float, u & 0xffff0000u);
        Wqd[(size_t)r * 1024 + c]       = (short)(u >> 16);
        Wqd[(size_t)r * 1024 + 512 + c] = (short)f2bf(f - fhi);
    } else {                                             // Wproj: 512*512, hi only
        int j = i - 2883584;
        Wpd[j] = (short)(__builtin_bit_cast(unsigned int, Wp[j]) >> 16);
    }
}

// ---------- qkv GEMM: M=4096 N=1536 K=1024, BM=128 BN=96 BK=64, XOR-swizzled LDS ----------
// LDS chunk layout: global (row r, col-chunk g) stored at phys chunk (g ^ (r&7)) within row.
// Frag reads then hit 8 distinct bank groups (2-way aliasing = free) instead of 16-way.
__global__ __launch_bounds__(256) void k_gemm_qkv(const short* __restrict__ A,
                                                  const short* __restrict__ B,
                                                  float* __restrict__ C,
                                                  float* __restrict__ psum,
                                                  float* __restrict__ psq) {
    __shared__ __align__(16) short As[128 * 64];   // 16 KB
    __shared__ __align__(16) short Bs[96 * 64];    // 12 KB
    const int tid  = threadIdx.x;
    const int lane = tid & 63, wv = tid >> 6;
    const int wy = wv >> 1, wx = wv & 1;
    const int quad = lane >> 4, l16 = lane & 15;
    const int m0 = blockIdx.y * 128, n0 = blockIdx.x * 96;
    const int K = 1024, N = 1536;

    f32x4 acc[4][3];
    #pragma unroll
    for (int i = 0; i < 4; ++i)
        #pragma unroll
        for (int j = 0; j < 3; ++j)
            #pragma unroll
            for (int r = 0; r < 4; ++r) acc[i][j][r] = 0.f;

    // staging: chunk c (16B) = L*64 + lane; row = c>>3, logical col-chunk = c&7,
    // global col-chunk fetched = (c&7) ^ (row&7)  [XOR swizzle]
    const short* gA[4]; short* lA[4];
    #pragma unroll
    for (int i = 0; i < 4; ++i) {
        int L = wv + 4 * i;                  // 16 wave-loads for A
        int c = L * 64 + lane;
        int r = c >> 3, g = (c & 7) ^ (r & 7);
        gA[i] = A + (size_t)(m0 + r) * K + g * 8;
        lA[i] = &As[L * 512];
    }
    const short* gB[3]; short* lB[3];
    #pragma unroll
    for (int i = 0; i < 3; ++i) {
        int L = wv + 4 * i;                  // 12 wave-loads for B
        int c = L * 64 + lane;
        int r = c >> 3, g = (c & 7) ^ (r & 7);
        gB[i] = B + (size_t)(n0 + r) * K + g * 8;
        lB[i] = &Bs[L * 512];
    }

    for (int k0 = 0; k0 < K; k0 += 64) {
        __syncthreads();
        #pragma unroll
        for (int i = 0; i < 4; ++i) GLOAD_LDS16(gA[i] + k0, lA[i]);
        #pragma unroll
        for (int i = 0; i < 3; ++i) GLOAD_LDS16(gB[i] + k0, lB[i]);
        __syncthreads();
        #pragma unroll
        for (int sub = 0; sub < 2; ++sub) {
            const int jc = (sub * 4 + quad) ^ (l16 & 7);   // swizzled frag col-chunk
            short8 aF[4], bF[3];
            #pragma unroll
            for (int mt = 0; mt < 4; ++mt)
                aF[mt] = *(const short8*)&As[(wy * 64 + mt * 16 + l16) * 64 + jc * 8];
            #pragma unroll
            for (int nt = 0; nt < 3; ++nt)
                bF[nt] = *(const short8*)&Bs[(wx * 48 + nt * 16 + l16) * 64 + jc * 8];
            #pragma unroll
            for (int mt = 0; mt < 4; ++mt)
                #pragma unroll
                for (int nt = 0; nt < 3; ++nt)
                    acc[mt][nt] = __builtin_amdgcn_mfma_f32_16x16x32_bf16(aF[mt], bF[nt], acc[mt][nt], 0, 0, 0);
        }
    }

    #pragma unroll
    for (int mt = 0; mt < 4; ++mt)
        #pragma unroll
        for (int r = 0; r < 4; ++r) {
            int row = m0 + wy * 64 + mt * 16 + quad * 4 + r;
            float* Cr = C + (size_t)row * N + n0 + wx * 48 + l16;
            #pragma unroll
            for (int nt = 0; nt < 3; ++nt) Cr[nt * 16] = acc[mt][nt][r];
        }

    // fused BN partial stats over this 128-row stripe (deterministic)
    __syncthreads();
    float* PS = (float*)As;   // [8][96]
    float* PQ = (float*)Bs;
    #pragma unroll
    for (int nt = 0; nt < 3; ++nt) {
        float s = 0.f, q = 0.f;
        #pragma unroll
        for (int mt = 0; mt < 4; ++mt)
            #pragma unroll
            for (int r = 0; r < 4; ++r) {
                float v = acc[mt][nt][r];
                s += v;
                q = fmaf(v, v, q);
            }
        PS[(wy * 4 + quad) * 96 + wx * 48 + nt * 16 + l16] = s;
        PQ[(wy * 4 + quad) * 96 + wx * 48 + nt * 16 + l16] = q;
    }
    __syncthreads();
    if (tid < 96) {
        float s = 0.f, q = 0.f;
        #pragma unroll
        for (int i = 0; i < 8; ++i) { s += PS[i * 96 + tid]; q += PQ[i * 96 + tid]; }
        psum[blockIdx.y * 1536 + n0 + tid] = s;
        psq [blockIdx.y * 1536 + n0 + tid] = q;
    }
}

// ---------- generic bf16 MFMA GEMM (round-5 proven; used for proj) ----------
template<bool BIAS, bool BNSTATS, int MT, int NT>
__global__ __launch_bounds__(256) void k_gemm_bf16(const short* __restrict__ A,
                                                   const short* __restrict__ B,
                                                   const float* __restrict__ bias,
                                                   float* __restrict__ C,
                                                   float* __restrict__ psum,
                                                   float* __restrict__ psq,
                                                   int M, int N, int K) {
    constexpr int BM = MT * 32, BN = NT * 32;
    __shared__ __align__(16) short As[BM * 32];
    __shared__ __align__(16) short Bs[BN * 32];
    const int tid  = threadIdx.x;
    const int lane = tid & 63, wv = tid >> 6;
    const int wy = wv >> 1, wx = wv & 1;
    const int quad = lane >> 4, l16 = lane & 15;
    const int m0 = blockIdx.y * BM, n0 = blockIdx.x * BN;

    f32x4 acc[MT][NT];
    #pragma unroll
    for (int i = 0; i < MT; ++i)
        #pragma unroll
        for (int j = 0; j < NT; ++j)
            #pragma unroll
            for (int r = 0; r < 4; ++r) acc[i][j][r] = 0.f;

    constexpr int LA = 2 * MT, LB = 2 * NT;
    const short* gA[(LA + 3) / 4]; short* lA[(LA + 3) / 4]; int nA = 0;
    #pragma unroll
    for (int L0 = 0; L0 < LA; L0 += 4) {
        int L = L0 + wv;
        if (L < LA) {
            int c = L * 64 + lane;
            gA[nA] = A + (size_t)(m0 + (c >> 2)) * K + (c & 3) * 8;
            lA[nA] = &As[L * 512];
            ++nA;
        }
    }
    const short* gB[(LB + 3) / 4]; short* lB[(LB + 3) / 4]; int nB = 0;
    #pragma unroll
    for (int L0 = 0; L0 < LB; L0 += 4) {
        int L = L0 + wv;
        if (L < LB) {
            int c = L * 64 + lane;
            gB[nB] = B + (size_t)(n0 + (c >> 2)) * K + (c & 3) * 8;
            lB[nB] = &Bs[L * 512];
            ++nB;
        }
    }

    for (int k0 = 0; k0 < K; k0 += 32) {
        __syncthreads();
        for (int i = 0; i < nA; ++i) GLOAD_LDS16(gA[i] + k0, lA[i]);
        for (int i = 0; i < nB; ++i) GLOAD_LDS16(gB[i] + k0, lB[i]);
        __syncthreads();
        short8 aF[MT], bF[NT];
        #pragma unroll
        for (int mt = 0; mt < MT; ++mt)
            aF[mt] = *(const short8*)&As[(wy * MT * 16 + mt * 16 + l16) * 32 + quad * 8];
        #pragma unroll
        for (int nt = 0; nt < NT; ++nt)
            bF[nt] = *(const short8*)&Bs[(wx * NT * 16 + nt * 16 + l16) * 32 + quad * 8];
        #pragma unroll
        for (int mt = 0; mt < MT; ++mt)
            #pragma unroll
            for (int nt = 0; nt < NT; ++nt)
                acc[mt][nt] = __builtin_amdgcn_mfma_f32_16x16x32_bf16(aF[mt], bF[nt], acc[mt][nt], 0, 0, 0);
    }

    float bs[NT];
    #pragma unroll
    for (int nt = 0; nt < NT; ++nt) bs[nt] = BIAS ? bias[n0 + wx * NT * 16 + nt * 16 + l16] : 0.f;
    #pragma unroll
    for (int mt = 0; mt < MT; ++mt)
        #pragma unroll
        for (int r = 0; r < 4; ++r) {
            int row = m0 + wy * MT * 16 + mt * 16 + quad * 4 + r;
            float* Cr = C + (size_t)row * N + n0 + wx * NT * 16 + l16;
            #pragma unroll
            for (int nt = 0; nt < NT; ++nt) Cr[nt * 16] = acc[mt][nt][r] + bs[nt];
        }

    if (BNSTATS) {
        __syncthreads();
        float* PS = (float*)As;
        float* PQ = (float*)Bs;
        #pragma unroll
        for (int nt = 0; nt < NT; ++nt) {
            float s = 0.f, q = 0.f;
            #pragma unroll
            for (int mt = 0; mt < MT; ++mt)
                #pragma unroll
                for (int r = 0; r < 4; ++r) {
                    float v = acc[mt][nt][r];
                    s += v;
                    q = fmaf(v, v, q);
                }
            PS[(wy * 4 + quad) * BN + wx * NT * 16 + nt * 16 + l16] = s;
            PQ[(wy * 4 + quad) * BN + wx * NT * 16 + nt * 16 + l16] = q;
        }
        __syncthreads();
        if (tid < BN) {
            float s = 0.f, q = 0.f;
            #pragma unroll
            for (int i = 0; i < 8; ++i) { s += PS[i * BN + tid]; q += PQ[i * BN + tid]; }
            psum[blockIdx.y * 1536 + n0 + tid] = s;
            psq [blockIdx.y * 1536 + n0 + tid] = q;
        }
    }
}

// ---------- fused BN finalize + spike + pack, channel-sliced (round-5 proven) ----------
__global__ __launch_bounds__(256) void k_bn_spike(const float* __restrict__ qkv,
                           const float* __restrict__ psum, const float* __restrict__ psq,
                           const float* __restrict__ gamma, const float* __restrict__ beta,
                           short* __restrict__ qp, short* __restrict__ kp, short* __restrict__ vt) {
    __shared__ float sa[64], sb[64];
    __shared__ short tile[64 * 72];
    const int tid = threadIdx.x;
    const int slice = blockIdx.x;            // 0..23
    const int c0 = slice * 64;
    const int r0 = blockIdx.y * 256;
    const int b = r0 >> 10, nb = r0 & 1023;

    if (tid < 64) {
        const int c = c0 + tid;
        double s = 0.0, q = 0.0;
        for (int st = 0; st < 32; ++st) { s += (double)psum[st * 1536 + c]; q += (double)psq[st * 1536 + c]; }
        const double mu  = s / 4096.0;
        const double var = q / 4096.0 - mu * mu;
        const float a = (float)((double)gamma[c] / sqrt(var + 1e-5));
        sa[tid] = a;
        sb[tid] = fmaf(-(float)mu, a, beta[c]);
    }
    __syncthreads();

    const int ch = tid & 63, rq = tid >> 6;
    const float A = sa[ch], Bsh = sb[ch];

    if (slice < 16) {
        const int h = slice & 7;
        short* base = (slice < 8 ? qp : kp) + (((size_t)b * 8 + h) * 1024 + nb) * 64;
        for (int i = rq; i < 256; i += 4) {
            float v = qkv[(size_t)(r0 + i) * 1536 + c0 + ch];
            base[(size_t)i * 64 + ch] = (short)f2bf(spikef(fmaf(v, A, Bsh)));
        }
    } else {
        const int h = slice - 16;
        const int e = tid >> 2, j0 = (tid & 3) * 16;
        short* vbase = vt + (((size_t)b * 8 + h) * 64 + e) * 1024 + nb;
        for (int rb = 0; rb < 4; ++rb) {
            __syncthreads();
            for (int i = rq; i < 64; i += 4) {
                float v = qkv[(size_t)(r0 + rb * 64 + i) * 1536 + c0 + ch];
                tile[ch * 72 + i] = (short)f2bf(spikef(fmaf(v, A, Bsh)));
            }
            __syncthreads();
            *(short8*)&vbase[rb * 64 + j0]     = *(const short8*)&tile[e * 72 + j0];
            *(short8*)&vbase[rb * 64 + j0 + 8] = *(const short8*)&tile[e * 72 + j0 + 8];
        }
    }
}

// ---------- fused MFMA attention (round-5 proven: S^T trick + per-wave scratch permute) ----------
__global__ __launch_bounds__(256) void k_attn(const short* __restrict__ qp,
                                              const short* __restrict__ kp,
                                              const short* __restrict__ vt,
                                              short* __restrict__ sout) {
    __shared__ __align__(16) short SM[26624];
    short* Qs = SM;                          // 64*72
    short* Ks = SM + 4608;                   // 128*72
    short* Vs = SM + 13824;                  // 64*136
    unsigned int* SC = (unsigned int*)(SM + 22528);
    const int tid  = threadIdx.x;
    const int lane = tid & 63, w = tid >> 6;
    const int quad = lane >> 4, l16 = lane & 15;
    const int b = blockIdx.z, h = blockIdx.y;
    const int n0 = blockIdx.x * 64;
    const size_t bh = (size_t)b * 8 + h;

    {
        const int row = tid >> 2, c0 = (tid & 3) * 16;
        const short* g = qp + (bh * 1024 + n0 + row) * 64 + c0;
        *(short8*)&Qs[row * 72 + c0]     = *(const short8*)(g);
        *(short8*)&Qs[row * 72 + c0 + 8] = *(const short8*)(g + 8);
    }
    __syncthreads();
    short8 qf[4][2];
    #pragma unroll
    for (int mt = 0; mt < 4; ++mt)
        #pragma unroll
        for (int kq = 0; kq < 2; ++kq)
            qf[mt][kq] = *(const short8*)&Qs[(mt * 16 + l16) * 72 + kq * 32 + quad * 8];

    f32x4 of[4][4];
    #pragma unroll
    for (int et = 0; et < 4; ++et)
        #pragma unroll
        for (int mt = 0; mt < 4; ++mt)
            #pragma unroll
            for (int r = 0; r < 4; ++r) of[et][mt][r] = 0.f;

    const int krow = tid >> 1, kc0 = (tid & 1) * 32;
    const int ve = tid >> 2,  vc0 = (tid & 3) * 32;
    unsigned int* buf0 = SC + w * 256;
    unsigned int* buf1 = SC + 1024 + w * 256;
    const int s0 = (l16 + 16 * ((2 * quad) & 3)) * 4 + (quad >> 1) * 2;
    const int s1 = (l16 + 16 * ((2 * quad + 1) & 3)) * 4 + (quad >> 1) * 2;

    for (int j0 = 0; j0 < 1024; j0 += 128) {
        __syncthreads();
        {
            const short* g = kp + (bh * 1024 + j0 + krow) * 64 + kc0;
            #pragma unroll
            for (int i = 0; i < 4; ++i)
                *(short8*)&Ks[krow * 72 + kc0 + i * 8] = *(const short8*)(g + i * 8);
            const short* gv = vt + (bh * 64 + ve) * 1024 + j0 + vc0;
            #pragma unroll
            for (int i = 0; i < 4; ++i)
                *(short8*)&Vs[ve * 136 + vc0 + i * 8] = *(const short8*)(gv + i * 8);
        }
        __syncthreads();

        f32x4 sacc[4][2];
        #pragma unroll
        for (int mt = 0; mt < 4; ++mt)
            #pragma unroll
            for (int nt = 0; nt < 2; ++nt)
                #pragma unroll
                for (int r = 0; r < 4; ++r) sacc[mt][nt][r] = 0.f;
        #pragma unroll
        for (int kq = 0; kq < 2; ++kq) {
            short8 kf0 = *(const short8*)&Ks[(w * 32 +      l16) * 72 + kq * 32 + quad * 8];
            short8 kf1 = *(const short8*)&Ks[(w * 32 + 16 + l16) * 72 + kq * 32 + quad * 8];
            #pragma unroll
            for (int mt = 0; mt < 4; ++mt) {
                sacc[mt][0] = __builtin_amdgcn_mfma_f32_16x16x32_bf16(kf0, qf[mt][kq], sacc[mt][0], 0, 0, 0);
                sacc[mt][1] = __builtin_amdgcn_mfma_f32_16x16x32_bf16(kf1, qf[mt][kq], sacc[mt][1], 0, 0, 0);
            }
        }
        short8 aS[4];
        #pragma unroll
        for (int mt = 0; mt < 4; ++mt) {
            unsigned int pk[4];
            #pragma unroll
            for (int nt = 0; nt < 2; ++nt)
                #pragma unroll
                for (int rp = 0; rp < 2; ++rp) {
                    unsigned int lo = f2bf(spikef(sacc[mt][nt][2 * rp]));
                    unsigned int hi = f2bf(spikef(sacc[mt][nt][2 * rp + 1]));
                    pk[nt * 2 + rp] = lo | (hi << 16);
                }
            unsigned int* buf = (mt & 1) ? buf1 : buf0;
            u32x2 wa; wa.x = pk[0]; wa.y = pk[1];
            u32x2 wb; wb.x = pk[2]; wb.y = pk[3];
            *(u32x2*)&buf[lane * 4]     = wa;
            *(u32x2*)&buf[lane * 4 + 2] = wb;
            if (mt > 0) {
                unsigned int* pb = (mt & 1) ? buf0 : buf1;
                u32x2 lo = *(const u32x2*)&pb[s0];
                u32x2 hi = *(const u32x2*)&pb[s1];
                u32x4 t; t.x = lo.x; t.y = lo.y; t.z = hi.x; t.w = hi.y;
                aS[mt - 1] = __builtin_bit_cast(short8, t);
            }
        }
        {
            u32x2 lo = *(const u32x2*)&buf1[s0];
            u32x2 hi = *(const u32x2*)&buf1[s1];
            u32x4 t; t.x = lo.x; t.y = lo.y; t.z = hi.x; t.w = hi.y;
            aS[3] = __builtin_bit_cast(short8, t);
        }

        #pragma unroll
        for (int et = 0; et < 4; ++et) {
            short8 bV = *(const short8*)&Vs[(et * 16 + l16) * 136 + w * 32 + quad * 8];
            #pragma unroll
            for (int mt = 0; mt < 4; ++mt)
                of[et][mt] = __builtin_amdgcn_mfma_f32_16x16x32_bf16(aS[mt], bV, of[et][mt], 0, 0, 0);
        }
    }

    __syncthreads();
    float* P2 = (float*)Ks;
    float* P3 = (float*)Vs;
    if (w == 2 || w == 3) {
        float* P = (w == 2) ? P2 : P3;
        #pragma unroll
        for (int et = 0; et < 4; ++et)
            #pragma unroll
            for (int mt = 0; mt < 4; ++mt)
                *(f32x4*)&P[(et * 16 + l16) * 68 + mt * 16 + quad * 4] = of[et][mt];
    }
    __syncthreads();
    if (w == 0 || w == 1) {
        float* P = (w == 0) ? P2 : P3;
        #pragma unroll
        for (int et = 0; et < 4; ++et)
            #pragma unroll
            for (int mt = 0; mt < 4; ++mt) {
                f32x4 t = *(const f32x4*)&P[(et * 16 + l16) * 68 + mt * 16 + quad * 4];
                #pragma unroll
                for (int r = 0; r < 4; ++r) of[et][mt][r] += t[r];
            }
    }
    __syncthreads();
    if (w == 1) {
        #pragma unroll
        for (int et = 0; et < 4; ++et)
            #pragma unroll
            for (int mt = 0; mt < 4; ++mt)
                *(f32x4*)&P2[(et * 16 + l16) * 68 + mt * 16 + quad * 4] = of[et][mt];
    }
    __syncthreads();
    if (w == 0) {
        #pragma unroll
        for (int et = 0; et < 4; ++et)
            #pragma unroll
            for (int mt = 0; mt < 4; ++mt) {
                f32x4 t = *(const f32x4*)&P2[(et * 16 + l16) * 68 + mt * 16 + quad * 4];
                #pragma unroll
                for (int r = 0; r < 4; ++r) {
                    size_t orow = (size_t)b * 1024 + n0 + mt * 16 + quad * 4 + r;
                    sout[orow * 512 + h * 64 + et * 16 + l16] =
                        (short)f2bf(spikef((of[et][mt][r] + t[r]) * 0.125f));
                }
            }
    }
}

extern "C" void kernel_launch(void* const* d_in, const int* in_sizes, int n_in,
                              void* d_out, int out_size, void* d_ws, size_t ws_size,
                              hipStream_t stream) {
    const float* x     = (const float*)d_in[0];
    const float* Wqkv  = (const float*)d_in[1];
    const float* gamma = (const float*)d_in[2];
    const float* beta  = (const float*)d_in[3];
    const float* Wproj = (const float*)d_in[4];
    const float* bproj = (const float*)d_in[5];
    float* out = (float*)d_out;

    char* w = (char*)d_ws;
    short* xs2    = (short*)(w);                  // 8 MB; front 4 MB reused as sout
    short* Wqkv2  = (short*)(w + 8388608);        // 3 MB
    short* Wproj2 = (short*)(w + 11534336);       // 0.5 MB
    float* qkv    = (float*)(w + 12582912);       // 24 MB
    short* qp     = (short*)(w + 37748736);       // 4 MB
    short* kp     = (short*)(w + 41943040);       // 4 MB
    short* vt     = (short*)(w + 46137344);       // 4 MB
    float* psum   = (float*)(w + 50331648);
    float* psq    = psum + 32 * 1536;
    short* sout   = xs2;

    k_prep<<<12288, 256, 0, stream>>>(x, Wqkv, Wproj, xs2, Wqkv2, Wproj2);
    k_gemm_qkv<<<dim3(16, 32), 256, 0, stream>>>(xs2, Wqkv2, qkv, psum, psq);
    k_bn_spike<<<dim3(24, 16), 256, 0, stream>>>(qkv, psum, psq, gamma, beta, qp, kp, vt);
    k_attn<<<dim3(16, 8, 4), 256, 0, stream>>>(qp, kp, vt, sout);
    k_gemm_bf16<true, false, 1, 4><<<dim3(4, 128), 256, 0, stream>>>(
        sout, Wproj2, bproj, out, nullptr, nullptr, 4096, 512, 512);
}

// Round 9
// 133.918 us; speedup vs baseline: 1.6105x; 1.0691x over previous
//
#include <hip/hip_runtime.h>

typedef __attribute__((ext_vector_type(8))) short short8;
typedef __attribute__((ext_vector_type(4))) float f32x4;
typedef __attribute__((ext_vector_type(4))) int int4v;
typedef __attribute__((ext_vector_type(4))) unsigned int u32x4;

#define THRE 4.0f

#define GLOAD_LDS16(g, l) \
    __builtin_amdgcn_global_load_lds((const __attribute__((address_space(1))) void*)(g), \
                                     (__attribute__((address_space(3))) void*)(l), 16, 0, 0)

__device__ __forceinline__ float spikef(float x) {
    return floorf(fminf(fmaxf(x, 0.0f), THRE) + 0.5f);
}
__device__ __forceinline__ unsigned short f2bf(float f) {   // truncate; exact for small ints
    return (unsigned short)(__builtin_bit_cast(unsigned int, f) >> 16);
}
__device__ __forceinline__ int4v mfma_i8(u32x4 a, u32x4 b, int4v c) {
    return __builtin_amdgcn_mfma_i32_16x16x64_i8(__builtin_bit_cast(int4v, a),
                                                 __builtin_bit_cast(int4v, b), c, 0, 0, 0);
}

// ---------- prep: spike(x)->bf16 (single copy); Wqkv -> bf16 hi|lo; Wproj -> hi ----------
__global__ void k_prep(const float* __restrict__ x,
                       const float* __restrict__ Wq, const float* __restrict__ Wp,
                       short* __restrict__ xs, short* __restrict__ Wqd, short* __restrict__ Wpd) {
    int i = blockIdx.x * 256 + threadIdx.x;             // 12288 blocks
    if (i < 2097152) {                                   // x: 4096*512 flat
        xs[i] = (short)f2bf(spikef(x[i]));
    } else if (i < 2883584) {                            // Wqkv: 1536*512, hi|lo [r][2K]
        int j = i - 2097152;
        int r = j >> 9, c = j & 511;
        float f = Wq[j];
        unsigned u = __builtin_bit_cast(unsigned int, f);
        float fhi = __builtin_bit_cast(float, u & 0xffff0000u);
        Wqd[(size_t)r * 1024 + c]       = (short)(u >> 16);
        Wqd[(size_t)r * 1024 + 512 + c] = (short)f2bf(f - fhi);
    } else {                                             // Wproj: 512*512, hi only
        int j = i - 2883584;
        Wpd[j] = (short)(__builtin_bit_cast(unsigned int, Wp[j]) >> 16);
    }
}

// ---------- qkv GEMM: M=4096 N=1536 K=1024 (A halves duplicated via k0&511) ----------
// BM=128 BN=96 BK=64, XOR-swizzled LDS chunks -> conflict-free frag reads.
__global__ __launch_bounds__(256) void k_gemm_qkv(const short* __restrict__ A,
                                                  const short* __restrict__ B,
                                                  float* __restrict__ C,
                                                  float* __restrict__ psum,
                                                  float* __restrict__ psq) {
    __shared__ __align__(16) short As[128 * 64];   // 16 KB
    __shared__ __align__(16) short Bs[96 * 64];    // 12 KB
    const int tid  = threadIdx.x;
    const int lane = tid & 63, wv = tid >> 6;
    const int wy = wv >> 1, wx = wv & 1;
    const int quad = lane >> 4, l16 = lane & 15;
    const int m0 = blockIdx.y * 128, n0 = blockIdx.x * 96;
    const int K = 1024, N = 1536;

    f32x4 acc[4][3];
    #pragma unroll
    for (int i = 0; i < 4; ++i)
        #pragma unroll
        for (int j = 0; j < 3; ++j)
            #pragma unroll
            for (int r = 0; r < 4; ++r) acc[i][j][r] = 0.f;

    // staging: chunk c = L*64 + lane; row = c>>3, logical col-chunk = c&7,
    // global col-chunk fetched = (c&7) ^ (row&7)  [XOR swizzle]
    const short* gA[4]; short* lA[4];
    #pragma unroll
    for (int i = 0; i < 4; ++i) {
        int L = wv + 4 * i;
        int c = L * 64 + lane;
        int r = c >> 3, g = (c & 7) ^ (r & 7);
        gA[i] = A + (size_t)(m0 + r) * 512 + g * 8;    // xs row stride 512 (single copy)
        lA[i] = &As[L * 512];
    }
    const short* gB[3]; short* lB[3];
    #pragma unroll
    for (int i = 0; i < 3; ++i) {
        int L = wv + 4 * i;
        int c = L * 64 + lane;
        int r = c >> 3, g = (c & 7) ^ (r & 7);
        gB[i] = B + (size_t)(n0 + r) * K + g * 8;
        lB[i] = &Bs[L * 512];
    }

    for (int k0 = 0; k0 < K; k0 += 64) {
        const int ka = k0 & 511;                        // duplicated-half fold
        __syncthreads();
        #pragma unroll
        for (int i = 0; i < 4; ++i) GLOAD_LDS16(gA[i] + ka, lA[i]);
        #pragma unroll
        for (int i = 0; i < 3; ++i) GLOAD_LDS16(gB[i] + k0, lB[i]);
        __syncthreads();
        #pragma unroll
        for (int sub = 0; sub < 2; ++sub) {
            const int jc = (sub * 4 + quad) ^ (l16 & 7);
            short8 aF[4], bF[3];
            #pragma unroll
            for (int mt = 0; mt < 4; ++mt)
                aF[mt] = *(const short8*)&As[(wy * 64 + mt * 16 + l16) * 64 + jc * 8];
            #pragma unroll
            for (int nt = 0; nt < 3; ++nt)
                bF[nt] = *(const short8*)&Bs[(wx * 48 + nt * 16 + l16) * 64 + jc * 8];
            #pragma unroll
            for (int mt = 0; mt < 4; ++mt)
                #pragma unroll
                for (int nt = 0; nt < 3; ++nt)
                    acc[mt][nt] = __builtin_amdgcn_mfma_f32_16x16x32_bf16(aF[mt], bF[nt], acc[mt][nt], 0, 0, 0);
        }
    }

    #pragma unroll
    for (int mt = 0; mt < 4; ++mt)
        #pragma unroll
        for (int r = 0; r < 4; ++r) {
            int row = m0 + wy * 64 + mt * 16 + quad * 4 + r;
            float* Cr = C + (size_t)row * N + n0 + wx * 48 + l16;
            #pragma unroll
            for (int nt = 0; nt < 3; ++nt) Cr[nt * 16] = acc[mt][nt][r];
        }

    // fused BN partial stats over this 128-row stripe (deterministic)
    __syncthreads();
    float* PS = (float*)As;   // [8][96]
    float* PQ = (float*)Bs;
    #pragma unroll
    for (int nt = 0; nt < 3; ++nt) {
        float s = 0.f, q = 0.f;
        #pragma unroll
        for (int mt = 0; mt < 4; ++mt)
            #pragma unroll
            for (int r = 0; r < 4; ++r) {
                float v = acc[mt][nt][r];
                s += v;
                q = fmaf(v, v, q);
            }
        PS[(wy * 4 + quad) * 96 + wx * 48 + nt * 16 + l16] = s;
        PQ[(wy * 4 + quad) * 96 + wx * 48 + nt * 16 + l16] = q;
    }
    __syncthreads();
    if (tid < 96) {
        float s = 0.f, q = 0.f;
        #pragma unroll
        for (int i = 0; i < 8; ++i) { s += PS[i * 96 + tid]; q += PQ[i * 96 + tid]; }
        psum[blockIdx.y * 1536 + n0 + tid] = s;
        psq [blockIdx.y * 1536 + n0 + tid] = q;
    }
}

// ---------- generic bf16 MFMA GEMM (round-5 proven; used for proj) ----------
template<bool BIAS, int MT, int NT>
__global__ __launch_bounds__(256) void k_gemm_bf16(const short* __restrict__ A,
                                                   const short* __restrict__ B,
                                                   const float* __restrict__ bias,
                                                   float* __restrict__ C,
                                                   int M, int N, int K) {
    constexpr int BM = MT * 32, BN = NT * 32;
    __shared__ __align__(16) short As[BM * 32];
    __shared__ __align__(16) short Bs[BN * 32];
    const int tid  = threadIdx.x;
    const int lane = tid & 63, wv = tid >> 6;
    const int wy = wv >> 1, wx = wv & 1;
    const int quad = lane >> 4, l16 = lane & 15;
    const int m0 = blockIdx.y * BM, n0 = blockIdx.x * BN;

    f32x4 acc[MT][NT];
    #pragma unroll
    for (int i = 0; i < MT; ++i)
        #pragma unroll
        for (int j = 0; j < NT; ++j)
            #pragma unroll
            for (int r = 0; r < 4; ++r) acc[i][j][r] = 0.f;

    constexpr int LA = 2 * MT, LB = 2 * NT;
    const short* gA[(LA + 3) / 4]; short* lA[(LA + 3) / 4]; int nA = 0;
    #pragma unroll
    for (int L0 = 0; L0 < LA; L0 += 4) {
        int L = L0 + wv;
        if (L < LA) {
            int c = L * 64 + lane;
            gA[nA] = A + (size_t)(m0 + (c >> 2)) * K + (c & 3) * 8;
            lA[nA] = &As[L * 512];
            ++nA;
        }
    }
    const short* gB[(LB + 3) / 4]; short* lB[(LB + 3) / 4]; int nB = 0;
    #pragma unroll
    for (int L0 = 0; L0 < LB; L0 += 4) {
        int L = L0 + wv;
        if (L < LB) {
            int c = L * 64 + lane;
            gB[nB] = B + (size_t)(n0 + (c >> 2)) * K + (c & 3) * 8;
            lB[nB] = &Bs[L * 512];
            ++nB;
        }
    }

    for (int k0 = 0; k0 < K; k0 += 32) {
        __syncthreads();
        for (int i = 0; i < nA; ++i) GLOAD_LDS16(gA[i] + k0, lA[i]);
        for (int i = 0; i < nB; ++i) GLOAD_LDS16(gB[i] + k0, lB[i]);
        __syncthreads();
        short8 aF[MT], bF[NT];
        #pragma unroll
        for (int mt = 0; mt < MT; ++mt)
            aF[mt] = *(const short8*)&As[(wy * MT * 16 + mt * 16 + l16) * 32 + quad * 8];
        #pragma unroll
        for (int nt = 0; nt < NT; ++nt)
            bF[nt] = *(const short8*)&Bs[(wx * NT * 16 + nt * 16 + l16) * 32 + quad * 8];
        #pragma unroll
        for (int mt = 0; mt < MT; ++mt)
            #pragma unroll
            for (int nt = 0; nt < NT; ++nt)
                acc[mt][nt] = __builtin_amdgcn_mfma_f32_16x16x32_bf16(aF[mt], bF[nt], acc[mt][nt], 0, 0, 0);
    }

    float bs[NT];
    #pragma unroll
    for (int nt = 0; nt < NT; ++nt) bs[nt] = BIAS ? bias[n0 + wx * NT * 16 + nt * 16 + l16] : 0.f;
    #pragma unroll
    for (int mt = 0; mt < MT; ++mt)
        #pragma unroll
        for (int r = 0; r < 4; ++r) {
            int row = m0 + wy * MT * 16 + mt * 16 + quad * 4 + r;
            float* Cr = C + (size_t)row * N + n0 + wx * NT * 16 + l16;
            #pragma unroll
            for (int nt = 0; nt < NT; ++nt) Cr[nt * 16] = acc[mt][nt][r] + bs[nt];
        }
}

// ---------- BN finalize + spike + pack to i8 q/k (row-major) and v (transposed) ----------
__global__ __launch_bounds__(256) void k_bn_spike(const float* __restrict__ qkv,
                           const float* __restrict__ psum, const float* __restrict__ psq,
                           const float* __restrict__ gamma, const float* __restrict__ beta,
                           unsigned char* __restrict__ qp, unsigned char* __restrict__ kp,
                           unsigned char* __restrict__ vt) {
    __shared__ float sa[64], sb[64];
    __shared__ __align__(16) unsigned char tile[64 * 80];   // v^T staging, rows 80B (16B-aligned)
    const int tid = threadIdx.x;
    const int slice = blockIdx.x;            // 0..23
    const int c0 = slice * 64;
    const int r0 = blockIdx.y * 256;
    const int b = r0 >> 10, nb = r0 & 1023;

    if (tid < 64) {
        const int c = c0 + tid;
        double s = 0.0, q = 0.0;
        for (int st = 0; st < 32; ++st) { s += (double)psum[st * 1536 + c]; q += (double)psq[st * 1536 + c]; }
        const double mu  = s / 4096.0;
        const double var = q / 4096.0 - mu * mu;
        const float a = (float)((double)gamma[c] / sqrt(var + 1e-5));
        sa[tid] = a;
        sb[tid] = fmaf(-(float)mu, a, beta[c]);
    }
    __syncthreads();

    const int ch = tid & 63, rq = tid >> 6;
    const float A = sa[ch], Bsh = sb[ch];

    if (slice < 16) {
        const int h = slice & 7;
        unsigned char* base = (slice < 8 ? qp : kp) + (((size_t)b * 8 + h) * 1024 + nb) * 64;
        for (int i = rq; i < 256; i += 4) {
            float v = qkv[(size_t)(r0 + i) * 1536 + c0 + ch];
            base[(size_t)i * 64 + ch] = (unsigned char)spikef(fmaf(v, A, Bsh));
        }
    } else {
        const int h = slice - 16;
        const int e = tid >> 2, j0 = (tid & 3) * 16;
        unsigned char* vbase = vt + (((size_t)b * 8 + h) * 64 + e) * 1024 + nb;
        for (int rb = 0; rb < 4; ++rb) {
            __syncthreads();
            for (int i = rq; i < 64; i += 4) {
                float v = qkv[(size_t)(r0 + rb * 64 + i) * 1536 + c0 + ch];
                tile[ch * 80 + i] = (unsigned char)spikef(fmaf(v, A, Bsh));
            }
            __syncthreads();
            *(u32x4*)&vbase[rb * 64 + j0] = *(const u32x4*)&tile[e * 80 + j0];
        }
    }
}

// ---------- fused i8-MFMA attention: sout = spike(0.125 * spike(q k^T) v), exact ----------
// grid (16, 8, 4), 256 threads = 4 waves. Wave w: S^T for j-slice [w*32,w*32+32) via
// mfma_i32_16x16x64_i8 (K=64 = head dim, one MFMA); clamp to {0..4} (integer spike);
// pack 4 j-consecutive i8 per dword in-register -> Sb[64][36dw]; PV: wave w owns
// e-slice w*16, A-frags are clean b128 reads from Sb. All arithmetic integer-exact.
__global__ __launch_bounds__(256) void k_attn(const unsigned char* __restrict__ qp,
                                              const unsigned char* __restrict__ kp,
                                              const unsigned char* __restrict__ vt,
                                              short* __restrict__ sout) {
    __shared__ __align__(16) unsigned char SM[33792];
    unsigned char* Qs = SM;                        // 64 x 80B
    unsigned char* Ks = SM + 5120;                 // 128 x 80B
    unsigned char* Vs = SM + 15360;                // 64 x 144B
    unsigned int* Sb = (unsigned int*)(SM + 24576);// 64 x 36 dwords (rows 144B, 16B-aligned)
    const int tid  = threadIdx.x;
    const int lane = tid & 63, w = tid >> 6;
    const int quad = lane >> 4, l16 = lane & 15;
    const int b = blockIdx.z, h = blockIdx.y;
    const int n0 = blockIdx.x * 64;
    const size_t bh = (size_t)b * 8 + h;

    // stage Q (64 x 64B) once
    {
        const int row = tid >> 2, c0 = (tid & 3) * 16;
        *(u32x4*)&Qs[row * 80 + c0] = *(const u32x4*)(qp + (bh * 1024 + n0 + row) * 64 + c0);
    }
    __syncthreads();
    u32x4 qf[4];
    #pragma unroll
    for (int mt = 0; mt < 4; ++mt)
        qf[mt] = *(const u32x4*)&Qs[(mt * 16 + l16) * 80 + quad * 16];

    int4v of[4];
    #pragma unroll
    for (int mt = 0; mt < 4; ++mt)
        #pragma unroll
        for (int r = 0; r < 4; ++r) of[mt][r] = 0;

    const int krow = tid >> 1, kc0 = (tid & 1) * 32;
    const int ve = tid >> 2,  vc0 = (tid & 3) * 32;

    for (int j0 = 0; j0 < 1024; j0 += 128) {
        __syncthreads();   // prior iter's Sb/Vs reads done
        {
            const unsigned char* g = kp + (bh * 1024 + j0 + krow) * 64 + kc0;
            *(u32x4*)&Ks[krow * 80 + kc0]      = *(const u32x4*)(g);
            *(u32x4*)&Ks[krow * 80 + kc0 + 16] = *(const u32x4*)(g + 16);
            const unsigned char* gv = vt + (bh * 64 + ve) * 1024 + j0 + vc0;
            *(u32x4*)&Vs[ve * 144 + vc0]      = *(const u32x4*)(gv);
            *(u32x4*)&Vs[ve * 144 + vc0 + 16] = *(const u32x4*)(gv + 16);
        }
        __syncthreads();

        // S^T = K Q^T (this wave's 32 j-rows), spike = integer clamp, pack -> Sb
        #pragma unroll
        for (int jt = 0; jt < 2; ++jt) {
            u32x4 kf = *(const u32x4*)&Ks[(w * 32 + jt * 16 + l16) * 80 + quad * 16];
            #pragma unroll
            for (int mt = 0; mt < 4; ++mt) {
                int4v z;
                #pragma unroll
                for (int r = 0; r < 4; ++r) z[r] = 0;
                int4v s = mfma_i8(kf, qf[mt], z);
                unsigned int pk = 0;
                #pragma unroll
                for (int r = 0; r < 4; ++r) {
                    int v = s[r]; v = v < 0 ? 0 : (v > 4 ? 4 : v);
                    pk |= (unsigned int)v << (8 * r);
                }
                Sb[(mt * 16 + l16) * 36 + w * 8 + jt * 4 + quad] = pk;
            }
        }
        __syncthreads();

        // PV: out[m][e-slice w] += S~[m][0:128] V[0:128][e], K=64 per MFMA
        #pragma unroll
        for (int kk = 0; kk < 2; ++kk) {
            u32x4 bV = *(const u32x4*)&Vs[(w * 16 + l16) * 144 + kk * 64 + quad * 16];
            #pragma unroll
            for (int mt = 0; mt < 4; ++mt) {
                u32x4 aS = *(const u32x4*)&Sb[(mt * 16 + l16) * 36 + kk * 16 + quad * 4];
                of[mt] = mfma_i8(aS, bV, of[mt]);
            }
        }
    }

    // epilogue: spike(out/8) -> bf16 sout (each wave owns its e-slice; no reduce)
    #pragma unroll
    for (int mt = 0; mt < 4; ++mt)
        #pragma unroll
        for (int r = 0; r < 4; ++r) {
            size_t orow = (size_t)b * 1024 + n0 + mt * 16 + quad * 4 + r;
            sout[orow * 512 + h * 64 + w * 16 + l16] =
                (short)f2bf(spikef((float)of[mt][r] * 0.125f));
        }
}

extern "C" void kernel_launch(void* const* d_in, const int* in_sizes, int n_in,
                              void* d_out, int out_size, void* d_ws, size_t ws_size,
                              hipStream_t stream) {
    const float* x     = (const float*)d_in[0];
    const float* Wqkv  = (const float*)d_in[1];
    const float* gamma = (const float*)d_in[2];
    const float* beta  = (const float*)d_in[3];
    const float* Wproj = (const float*)d_in[4];
    const float* bproj = (const float*)d_in[5];
    float* out = (float*)d_out;

    char* w = (char*)d_ws;
    short* xs            = (short*)(w);                  // 4 MB [4096][512]; reused as sout
    short* Wqkv2         = (short*)(w + 8388608);        // 3 MB
    short* Wproj2        = (short*)(w + 11534336);       // 0.5 MB
    float* qkv           = (float*)(w + 12582912);       // 24 MB
    unsigned char* qp    = (unsigned char*)(w + 37748736);  // 2 MB
    unsigned char* kp    = (unsigned char*)(w + 41943040);  // 2 MB
    unsigned char* vt    = (unsigned char*)(w + 46137344);  // 2 MB
    float* psum          = (float*)(w + 50331648);
    float* psq           = psum + 32 * 1536;
    short* sout          = xs;                           // xs dead after qkv GEMM

    k_prep<<<12288, 256, 0, stream>>>(x, Wqkv, Wproj, xs, Wqkv2, Wproj2);
    k_gemm_qkv<<<dim3(16, 32), 256, 0, stream>>>(xs, Wqkv2, qkv, psum, psq);
    k_bn_spike<<<dim3(24, 16), 256, 0, stream>>>(qkv, psum, psq, gamma, beta, qp, kp, vt);
    k_attn<<<dim3(16, 8, 4), 256, 0, stream>>>(qp, kp, vt, sout);
    k_gemm_bf16<true, 1, 4><<<dim3(4, 128), 256, 0, stream>>>(
        sout, Wproj2, bproj, out, 4096, 512, 512);
}

// Round 10
// 126.368 us; speedup vs baseline: 1.7067x; 1.0597x over previous
//
#include <hip/hip_runtime.h>

typedef __attribute__((ext_vector_type(8))) short short8;
typedef __attribute__((ext_vector_type(4))) float f32x4;
typedef __attribute__((ext_vector_type(4))) int int4v;
typedef __attribute__((ext_vector_type(4))) unsigned int u32x4;

#define THRE 4.0f

#define GLOAD_LDS16(g, l) \
    __builtin_amdgcn_global_load_lds((const __attribute__((address_space(1))) void*)(g), \
                                     (__attribute__((address_space(3))) void*)(l), 16, 0, 0)

__device__ __forceinline__ float spikef(float x) {
    return floorf(fminf(fmaxf(x, 0.0f), THRE) + 0.5f);
}
__device__ __forceinline__ unsigned short f2bf(float f) {   // truncate; exact for small ints
    return (unsigned short)(__builtin_bit_cast(unsigned int, f) >> 16);
}
__device__ __forceinline__ int4v mfma_i8(u32x4 a, u32x4 b, int4v c) {
    return __builtin_amdgcn_mfma_i32_16x16x64_i8(__builtin_bit_cast(int4v, a),
                                                 __builtin_bit_cast(int4v, b), c, 0, 0, 0);
}

// ---------- prep: spike(x)->bf16; Wqkv -> bf16 hi only; Wproj -> hi only ----------
// Saturation analysis: qkv lo-term dropped — spike-boundary flips it could cause are
// absorbed by the S>=4.5 / out_pre>>4.5 clamps downstream; only the final GEMM needs
// precision, and it uses exact sout.
__global__ void k_prep(const float* __restrict__ x,
                       const float* __restrict__ Wq, const float* __restrict__ Wp,
                       short* __restrict__ xs, short* __restrict__ Wqd, short* __restrict__ Wpd) {
    int i = blockIdx.x * 256 + threadIdx.x;             // 12288 blocks = 3145728 threads
    if (i < 2097152) {                                   // x: 4096*512 flat
        xs[i] = (short)f2bf(spikef(x[i]));
    } else if (i < 2883584) {                            // Wqkv: 1536*512 -> hi bf16 flat
        int j = i - 2097152;
        Wqd[j] = (short)(__builtin_bit_cast(unsigned int, Wq[j]) >> 16);
    } else {                                             // Wproj: 512*512 -> hi bf16 flat
        int j = i - 2883584;
        Wpd[j] = (short)(__builtin_bit_cast(unsigned int, Wp[j]) >> 16);
    }
}

// ---------- qkv GEMM: M=4096 N=1536 K=512, BM=128 BN=96 BK=64, XOR-swizzled LDS ----------
__global__ __launch_bounds__(256) void k_gemm_qkv(const short* __restrict__ A,
                                                  const short* __restrict__ B,
                                                  float* __restrict__ C,
                                                  float* __restrict__ psum,
                                                  float* __restrict__ psq) {
    __shared__ __align__(16) short As[128 * 64];   // 16 KB
    __shared__ __align__(16) short Bs[96 * 64];    // 12 KB
    const int tid  = threadIdx.x;
    const int lane = tid & 63, wv = tid >> 6;
    const int wy = wv >> 1, wx = wv & 1;
    const int quad = lane >> 4, l16 = lane & 15;
    const int m0 = blockIdx.y * 128, n0 = blockIdx.x * 96;
    const int K = 512, N = 1536;

    f32x4 acc[4][3];
    #pragma unroll
    for (int i = 0; i < 4; ++i)
        #pragma unroll
        for (int j = 0; j < 3; ++j)
            #pragma unroll
            for (int r = 0; r < 4; ++r) acc[i][j][r] = 0.f;

    // staging: chunk c = L*64 + lane; row = c>>3, logical col-chunk = c&7,
    // global col-chunk fetched = (c&7) ^ (row&7)  [XOR swizzle]
    const short* gA[4]; short* lA[4];
    #pragma unroll
    for (int i = 0; i < 4; ++i) {
        int L = wv + 4 * i;
        int c = L * 64 + lane;
        int r = c >> 3, g = (c & 7) ^ (r & 7);
        gA[i] = A + (size_t)(m0 + r) * K + g * 8;
        lA[i] = &As[L * 512];
    }
    const short* gB[3]; short* lB[3];
    #pragma unroll
    for (int i = 0; i < 3; ++i) {
        int L = wv + 4 * i;
        int c = L * 64 + lane;
        int r = c >> 3, g = (c & 7) ^ (r & 7);
        gB[i] = B + (size_t)(n0 + r) * K + g * 8;
        lB[i] = &Bs[L * 512];
    }

    for (int k0 = 0; k0 < K; k0 += 64) {
        __syncthreads();
        #pragma unroll
        for (int i = 0; i < 4; ++i) GLOAD_LDS16(gA[i] + k0, lA[i]);
        #pragma unroll
        for (int i = 0; i < 3; ++i) GLOAD_LDS16(gB[i] + k0, lB[i]);
        __syncthreads();
        #pragma unroll
        for (int sub = 0; sub < 2; ++sub) {
            const int jc = (sub * 4 + quad) ^ (l16 & 7);
            short8 aF[4], bF[3];
            #pragma unroll
            for (int mt = 0; mt < 4; ++mt)
                aF[mt] = *(const short8*)&As[(wy * 64 + mt * 16 + l16) * 64 + jc * 8];
            #pragma unroll
            for (int nt = 0; nt < 3; ++nt)
                bF[nt] = *(const short8*)&Bs[(wx * 48 + nt * 16 + l16) * 64 + jc * 8];
            #pragma unroll
            for (int mt = 0; mt < 4; ++mt)
                #pragma unroll
                for (int nt = 0; nt < 3; ++nt)
                    acc[mt][nt] = __builtin_amdgcn_mfma_f32_16x16x32_bf16(aF[mt], bF[nt], acc[mt][nt], 0, 0, 0);
        }
    }

    #pragma unroll
    for (int mt = 0; mt < 4; ++mt)
        #pragma unroll
        for (int r = 0; r < 4; ++r) {
            int row = m0 + wy * 64 + mt * 16 + quad * 4 + r;
            float* Cr = C + (size_t)row * N + n0 + wx * 48 + l16;
            #pragma unroll
            for (int nt = 0; nt < 3; ++nt) Cr[nt * 16] = acc[mt][nt][r];
        }

    // fused BN partial stats over this 128-row stripe (deterministic)
    __syncthreads();
    float* PS = (float*)As;   // [8][96]
    float* PQ = (float*)Bs;
    #pragma unroll
    for (int nt = 0; nt < 3; ++nt) {
        float s = 0.f, q = 0.f;
        #pragma unroll
        for (int mt = 0; mt < 4; ++mt)
            #pragma unroll
            for (int r = 0; r < 4; ++r) {
                float v = acc[mt][nt][r];
                s += v;
                q = fmaf(v, v, q);
            }
        PS[(wy * 4 + quad) * 96 + wx * 48 + nt * 16 + l16] = s;
        PQ[(wy * 4 + quad) * 96 + wx * 48 + nt * 16 + l16] = q;
    }
    __syncthreads();
    if (tid < 96) {
        float s = 0.f, q = 0.f;
        #pragma unroll
        for (int i = 0; i < 8; ++i) { s += PS[i * 96 + tid]; q += PQ[i * 96 + tid]; }
        psum[blockIdx.y * 1536 + n0 + tid] = s;
        psq [blockIdx.y * 1536 + n0 + tid] = q;
    }
}

// ---------- generic bf16 MFMA GEMM (proj) ----------
template<bool BIAS, int MT, int NT>
__global__ __launch_bounds__(256) void k_gemm_bf16(const short* __restrict__ A,
                                                   const short* __restrict__ B,
                                                   const float* __restrict__ bias,
                                                   float* __restrict__ C,
                                                   int M, int N, int K) {
    constexpr int BM = MT * 32, BN = NT * 32;
    __shared__ __align__(16) short As[BM * 32];
    __shared__ __align__(16) short Bs[BN * 32];
    const int tid  = threadIdx.x;
    const int lane = tid & 63, wv = tid >> 6;
    const int wy = wv >> 1, wx = wv & 1;
    const int quad = lane >> 4, l16 = lane & 15;
    const int m0 = blockIdx.y * BM, n0 = blockIdx.x * BN;

    f32x4 acc[MT][NT];
    #pragma unroll
    for (int i = 0; i < MT; ++i)
        #pragma unroll
        for (int j = 0; j < NT; ++j)
            #pragma unroll
            for (int r = 0; r < 4; ++r) acc[i][j][r] = 0.f;

    constexpr int LA = 2 * MT, LB = 2 * NT;
    const short* gA[(LA + 3) / 4]; short* lA[(LA + 3) / 4]; int nA = 0;
    #pragma unroll
    for (int L0 = 0; L0 < LA; L0 += 4) {
        int L = L0 + wv;
        if (L < LA) {
            int c = L * 64 + lane;
            gA[nA] = A + (size_t)(m0 + (c >> 2)) * K + (c & 3) * 8;
            lA[nA] = &As[L * 512];
            ++nA;
        }
    }
    const short* gB[(LB + 3) / 4]; short* lB[(LB + 3) / 4]; int nB = 0;
    #pragma unroll
    for (int L0 = 0; L0 < LB; L0 += 4) {
        int L = L0 + wv;
        if (L < LB) {
            int c = L * 64 + lane;
            gB[nB] = B + (size_t)(n0 + (c >> 2)) * K + (c & 3) * 8;
            lB[nB] = &Bs[L * 512];
            ++nB;
        }
    }

    for (int k0 = 0; k0 < K; k0 += 32) {
        __syncthreads();
        for (int i = 0; i < nA; ++i) GLOAD_LDS16(gA[i] + k0, lA[i]);
        for (int i = 0; i < nB; ++i) GLOAD_LDS16(gB[i] + k0, lB[i]);
        __syncthreads();
        short8 aF[MT], bF[NT];
        #pragma unroll
        for (int mt = 0; mt < MT; ++mt)
            aF[mt] = *(const short8*)&As[(wy * MT * 16 + mt * 16 + l16) * 32 + quad * 8];
        #pragma unroll
        for (int nt = 0; nt < NT; ++nt)
            bF[nt] = *(const short8*)&Bs[(wx * NT * 16 + nt * 16 + l16) * 32 + quad * 8];
        #pragma unroll
        for (int mt = 0; mt < MT; ++mt)
            #pragma unroll
            for (int nt = 0; nt < NT; ++nt)
                acc[mt][nt] = __builtin_amdgcn_mfma_f32_16x16x32_bf16(aF[mt], bF[nt], acc[mt][nt], 0, 0, 0);
    }

    float bs[NT];
    #pragma unroll
    for (int nt = 0; nt < NT; ++nt) bs[nt] = BIAS ? bias[n0 + wx * NT * 16 + nt * 16 + l16] : 0.f;
    #pragma unroll
    for (int mt = 0; mt < MT; ++mt)
        #pragma unroll
        for (int r = 0; r < 4; ++r) {
            int row = m0 + wy * MT * 16 + mt * 16 + quad * 4 + r;
            float* Cr = C + (size_t)row * N + n0 + wx * NT * 16 + l16;
            #pragma unroll
            for (int nt = 0; nt < NT; ++nt) Cr[nt * 16] = acc[mt][nt][r] + bs[nt];
        }
}

// ---------- BN finalize + spike + pack to i8 q/k (row-major) and v (transposed) ----------
__global__ __launch_bounds__(256) void k_bn_spike(const float* __restrict__ qkv,
                           const float* __restrict__ psum, const float* __restrict__ psq,
                           const float* __restrict__ gamma, const float* __restrict__ beta,
                           unsigned char* __restrict__ qp, unsigned char* __restrict__ kp,
                           unsigned char* __restrict__ vt) {
    __shared__ float sa[64], sb[64];
    __shared__ __align__(16) unsigned char tile[64 * 80];
    const int tid = threadIdx.x;
    const int slice = blockIdx.x;            // 0..23
    const int c0 = slice * 64;
    const int r0 = blockIdx.y * 256;
    const int b = r0 >> 10, nb = r0 & 1023;

    if (tid < 64) {
        const int c = c0 + tid;
        double s = 0.0, q = 0.0;
        for (int st = 0; st < 32; ++st) { s += (double)psum[st * 1536 + c]; q += (double)psq[st * 1536 + c]; }
        const double mu  = s / 4096.0;
        const double var = q / 4096.0 - mu * mu;
        const float a = (float)((double)gamma[c] / sqrt(var + 1e-5));
        sa[tid] = a;
        sb[tid] = fmaf(-(float)mu, a, beta[c]);
    }
    __syncthreads();

    const int ch = tid & 63, rq = tid >> 6;
    const float A = sa[ch], Bsh = sb[ch];

    if (slice < 16) {
        const int h = slice & 7;
        unsigned char* base = (slice < 8 ? qp : kp) + (((size_t)b * 8 + h) * 1024 + nb) * 64;
        for (int i = rq; i < 256; i += 4) {
            float v = qkv[(size_t)(r0 + i) * 1536 + c0 + ch];
            base[(size_t)i * 64 + ch] = (unsigned char)spikef(fmaf(v, A, Bsh));
        }
    } else {
        const int h = slice - 16;
        const int e = tid >> 2, j0 = (tid & 3) * 16;
        unsigned char* vbase = vt + (((size_t)b * 8 + h) * 64 + e) * 1024 + nb;
        for (int rb = 0; rb < 4; ++rb) {
            __syncthreads();
            for (int i = rq; i < 64; i += 4) {
                float v = qkv[(size_t)(r0 + rb * 64 + i) * 1536 + c0 + ch];
                tile[ch * 80 + i] = (unsigned char)spikef(fmaf(v, A, Bsh));
            }
            __syncthreads();
            *(u32x4*)&vbase[rb * 64 + j0] = *(const u32x4*)&tile[e * 80 + j0];
        }
    }
}

// ---------- fused i8-MFMA attention with glds staging + XOR-swizzled LDS ----------
// Qs/Ks: 64B rows, phys chunk p holds logical g = p ^ (r&3) ^ ((r>>2)&3)  [2-way, free]
// Vs: 128B rows, p holds g = p ^ (r&7)                                    [2-way, free]
__global__ __launch_bounds__(256) void k_attn(const unsigned char* __restrict__ qp,
                                              const unsigned char* __restrict__ kp,
                                              const unsigned char* __restrict__ vt,
                                              short* __restrict__ sout) {
    __shared__ __align__(16) unsigned char SM[29696];
    unsigned char* Qs = SM;                        // 64 x 64B
    unsigned char* Ks = SM + 4096;                 // 128 x 64B
    unsigned char* Vs = SM + 12288;                // 64 x 128B
    unsigned int* Sb = (unsigned int*)(SM + 20480);// 64 x 36 dwords
    const int tid  = threadIdx.x;
    const int lane = tid & 63, w = tid >> 6;
    const int quad = lane >> 4, l16 = lane & 15;
    const int b = blockIdx.z, h = blockIdx.y;
    const int n0 = blockIdx.x * 64;
    const size_t bh = (size_t)b * 8 + h;

    // stage Q via glds (256 chunks, 1/thread)
    {
        const int r = tid >> 2, p = tid & 3;
        const int g = p ^ (r & 3) ^ ((r >> 2) & 3);
        GLOAD_LDS16(qp + (bh * 1024 + n0 + r) * 64 + g * 16, Qs + (size_t)tid * 16);
    }
    // K/V staging source pointers (2 chunks each per thread per tile)
    const unsigned char* gK[2]; unsigned char* lK[2];
    const unsigned char* gV[2]; unsigned char* lV[2];
    #pragma unroll
    for (int i = 0; i < 2; ++i) {
        int c = tid + 256 * i;
        int rk = c >> 2, pk2 = c & 3;
        int gk = pk2 ^ (rk & 3) ^ ((rk >> 2) & 3);
        gK[i] = kp + (bh * 1024 + rk) * 64 + gk * 16;
        lK[i] = Ks + (size_t)c * 16;
        int rv = c >> 3, pv = c & 7;
        int gv = pv ^ (rv & 7);
        gV[i] = vt + (bh * 64 + rv) * 1024 + gv * 16;
        lV[i] = Vs + (size_t)c * 16;
    }
    __syncthreads();
    u32x4 qf[4];
    {
        const int pq = quad ^ (l16 & 3) ^ ((l16 >> 2) & 3);
        #pragma unroll
        for (int mt = 0; mt < 4; ++mt)
            qf[mt] = *(const u32x4*)&Qs[(mt * 16 + l16) * 64 + pq * 16];
    }

    int4v of[4];
    #pragma unroll
    for (int mt = 0; mt < 4; ++mt)
        #pragma unroll
        for (int r = 0; r < 4; ++r) of[mt][r] = 0;

    const int pk = quad ^ (l16 & 3) ^ ((l16 >> 2) & 3);   // K frag phys chunk

    for (int j0 = 0; j0 < 1024; j0 += 128) {
        __syncthreads();   // prior iter's Sb/Vs reads done
        #pragma unroll
        for (int i = 0; i < 2; ++i) {
            GLOAD_LDS16(gK[i] + (size_t)j0 * 64, lK[i]);
            GLOAD_LDS16(gV[i] + j0, lV[i]);
        }
        __syncthreads();

        // S^T = K Q^T (this wave's 32 j-rows), integer spike clamp, pack -> Sb
        #pragma unroll
        for (int jt = 0; jt < 2; ++jt) {
            u32x4 kf = *(const u32x4*)&Ks[(w * 32 + jt * 16 + l16) * 64 + pk * 16];
            #pragma unroll
            for (int mt = 0; mt < 4; ++mt) {
                int4v z;
                #pragma unroll
                for (int r = 0; r < 4; ++r) z[r] = 0;
                int4v s = mfma_i8(kf, qf[mt], z);
                unsigned int pkk = 0;
                #pragma unroll
                for (int r = 0; r < 4; ++r) {
                    int v = s[r]; v = v < 0 ? 0 : (v > 4 ? 4 : v);
                    pkk |= (unsigned int)v << (8 * r);
                }
                Sb[(mt * 16 + l16) * 36 + w * 8 + jt * 4 + quad] = pkk;
            }
        }
        __syncthreads();

        // PV: out[m][e-slice w] += S~[m][0:128] V[0:128][e]
        #pragma unroll
        for (int kk = 0; kk < 2; ++kk) {
            const int pv = (kk * 4 + quad) ^ (l16 & 7);
            u32x4 bV = *(const u32x4*)&Vs[(w * 16 + l16) * 128 + pv * 16];
            #pragma unroll
            for (int mt = 0; mt < 4; ++mt) {
                u32x4 aS = *(const u32x4*)&Sb[(mt * 16 + l16) * 36 + kk * 16 + quad * 4];
                of[mt] = mfma_i8(aS, bV, of[mt]);
            }
        }
    }

    // epilogue: spike(out/8) -> bf16 sout (each wave owns its e-slice; no reduce)
    #pragma unroll
    for (int mt = 0; mt < 4; ++mt)
        #pragma unroll
        for (int r = 0; r < 4; ++r) {
            size_t orow = (size_t)b * 1024 + n0 + mt * 16 + quad * 4 + r;
            sout[orow * 512 + h * 64 + w * 16 + l16] =
                (short)f2bf(spikef((float)of[mt][r] * 0.125f));
        }
}

extern "C" void kernel_launch(void* const* d_in, const int* in_sizes, int n_in,
                              void* d_out, int out_size, void* d_ws, size_t ws_size,
                              hipStream_t stream) {
    const float* x     = (const float*)d_in[0];
    const float* Wqkv  = (const float*)d_in[1];
    const float* gamma = (const float*)d_in[2];
    const float* beta  = (const float*)d_in[3];
    const float* Wproj = (const float*)d_in[4];
    const float* bproj = (const float*)d_in[5];
    float* out = (float*)d_out;

    char* w = (char*)d_ws;
    short* xs            = (short*)(w);                     // 4 MB; reused as sout
    short* Wqkv2         = (short*)(w + 8388608);           // 1.5 MB (hi only)
    short* Wproj2        = (short*)(w + 11534336);          // 0.5 MB
    float* qkv           = (float*)(w + 12582912);          // 24 MB
    unsigned char* qp    = (unsigned char*)(w + 37748736);  // 2 MB
    unsigned char* kp    = (unsigned char*)(w + 41943040);  // 2 MB
    unsigned char* vt    = (unsigned char*)(w + 46137344);  // 2 MB
    float* psum          = (float*)(w + 50331648);
    float* psq           = psum + 32 * 1536;
    short* sout          = xs;                              // xs dead after qkv GEMM

    k_prep<<<12288, 256, 0, stream>>>(x, Wqkv, Wproj, xs, Wqkv2, Wproj2);
    k_gemm_qkv<<<dim3(16, 32), 256, 0, stream>>>(xs, Wqkv2, qkv, psum, psq);
    k_bn_spike<<<dim3(24, 16), 256, 0, stream>>>(qkv, psum, psq, gamma, beta, qp, kp, vt);
    k_attn<<<dim3(16, 8, 4), 256, 0, stream>>>(qp, kp, vt, sout);
    k_gemm_bf16<true, 1, 4><<<dim3(4, 128), 256, 0, stream>>>(
        sout, Wproj2, bproj, out, 4096, 512, 512);
}

// Round 11
// 120.893 us; speedup vs baseline: 1.7840x; 1.0453x over previous
//
#include <hip/hip_runtime.h>

typedef __attribute__((ext_vector_type(8))) short short8;
typedef __attribute__((ext_vector_type(4))) float f32x4;
typedef __attribute__((ext_vector_type(4))) int int4v;
typedef __attribute__((ext_vector_type(4))) unsigned int u32x4;

#define THRE 4.0f

#define GLOAD_LDS16(g, l) \
    __builtin_amdgcn_global_load_lds((const __attribute__((address_space(1))) void*)(g), \
                                     (__attribute__((address_space(3))) void*)(l), 16, 0, 0)

__device__ __forceinline__ float spikef(float x) {
    return floorf(fminf(fmaxf(x, 0.0f), THRE) + 0.5f);
}
__device__ __forceinline__ unsigned short f2bf(float f) {   // truncate; exact for small ints
    return (unsigned short)(__builtin_bit_cast(unsigned int, f) >> 16);
}
__device__ __forceinline__ unsigned short f2bf_rn(float f) { // round-to-nearest
    unsigned u = __builtin_bit_cast(unsigned int, f);
    unsigned r = ((u >> 16) & 1u) + 0x7FFFu;
    return (unsigned short)((u + r) >> 16);
}
__device__ __forceinline__ float bf2f(unsigned short s) {
    return __builtin_bit_cast(float, (unsigned int)s << 16);
}
__device__ __forceinline__ int4v mfma_i8(u32x4 a, u32x4 b, int4v c) {
    return __builtin_amdgcn_mfma_i32_16x16x64_i8(__builtin_bit_cast(int4v, a),
                                                 __builtin_bit_cast(int4v, b), c, 0, 0, 0);
}

// ---------- prep: spike(x)->bf16; Wqkv/Wproj -> bf16 hi only ----------
__global__ void k_prep(const float* __restrict__ x,
                       const float* __restrict__ Wq, const float* __restrict__ Wp,
                       short* __restrict__ xs, short* __restrict__ Wqd, short* __restrict__ Wpd) {
    int i = blockIdx.x * 256 + threadIdx.x;
    if (i < 2097152) {
        xs[i] = (short)f2bf(spikef(x[i]));
    } else if (i < 2883584) {
        int j = i - 2097152;
        Wqd[j] = (short)(__builtin_bit_cast(unsigned int, Wq[j]) >> 16);
    } else {
        int j = i - 2883584;
        Wpd[j] = (short)(__builtin_bit_cast(unsigned int, Wp[j]) >> 16);
    }
}

// ---------- qkv GEMM: M=4096 N=1536 K=512, BM=128 BN=96 BK=64; bf16 output ----------
// BN stats from fp32 accumulators (exact); C stored bf16-rn (error clamp-absorbed).
__global__ __launch_bounds__(256) void k_gemm_qkv(const short* __restrict__ A,
                                                  const short* __restrict__ B,
                                                  short* __restrict__ C,
                                                  float* __restrict__ psum,
                                                  float* __restrict__ psq) {
    __shared__ __align__(16) short As[128 * 64];
    __shared__ __align__(16) short Bs[96 * 64];
    const int tid  = threadIdx.x;
    const int lane = tid & 63, wv = tid >> 6;
    const int wy = wv >> 1, wx = wv & 1;
    const int quad = lane >> 4, l16 = lane & 15;
    const int m0 = blockIdx.y * 128, n0 = blockIdx.x * 96;
    const int K = 512, N = 1536;

    f32x4 acc[4][3];
    #pragma unroll
    for (int i = 0; i < 4; ++i)
        #pragma unroll
        for (int j = 0; j < 3; ++j)
            #pragma unroll
            for (int r = 0; r < 4; ++r) acc[i][j][r] = 0.f;

    const short* gA[4]; short* lA[4];
    #pragma unroll
    for (int i = 0; i < 4; ++i) {
        int L = wv + 4 * i;
        int c = L * 64 + lane;
        int r = c >> 3, g = (c & 7) ^ (r & 7);
        gA[i] = A + (size_t)(m0 + r) * K + g * 8;
        lA[i] = &As[L * 512];
    }
    const short* gB[3]; short* lB[3];
    #pragma unroll
    for (int i = 0; i < 3; ++i) {
        int L = wv + 4 * i;
        int c = L * 64 + lane;
        int r = c >> 3, g = (c & 7) ^ (r & 7);
        gB[i] = B + (size_t)(n0 + r) * K + g * 8;
        lB[i] = &Bs[L * 512];
    }

    for (int k0 = 0; k0 < K; k0 += 64) {
        __syncthreads();
        #pragma unroll
        for (int i = 0; i < 4; ++i) GLOAD_LDS16(gA[i] + k0, lA[i]);
        #pragma unroll
        for (int i = 0; i < 3; ++i) GLOAD_LDS16(gB[i] + k0, lB[i]);
        __syncthreads();
        #pragma unroll
        for (int sub = 0; sub < 2; ++sub) {
            const int jc = (sub * 4 + quad) ^ (l16 & 7);
            short8 aF[4], bF[3];
            #pragma unroll
            for (int mt = 0; mt < 4; ++mt)
                aF[mt] = *(const short8*)&As[(wy * 64 + mt * 16 + l16) * 64 + jc * 8];
            #pragma unroll
            for (int nt = 0; nt < 3; ++nt)
                bF[nt] = *(const short8*)&Bs[(wx * 48 + nt * 16 + l16) * 64 + jc * 8];
            #pragma unroll
            for (int mt = 0; mt < 4; ++mt)
                #pragma unroll
                for (int nt = 0; nt < 3; ++nt)
                    acc[mt][nt] = __builtin_amdgcn_mfma_f32_16x16x32_bf16(aF[mt], bF[nt], acc[mt][nt], 0, 0, 0);
        }
    }

    #pragma unroll
    for (int mt = 0; mt < 4; ++mt)
        #pragma unroll
        for (int r = 0; r < 4; ++r) {
            int row = m0 + wy * 64 + mt * 16 + quad * 4 + r;
            short* Cr = C + (size_t)row * N + n0 + wx * 48 + l16;
            #pragma unroll
            for (int nt = 0; nt < 3; ++nt) Cr[nt * 16] = (short)f2bf_rn(acc[mt][nt][r]);
        }

    __syncthreads();
    float* PS = (float*)As;   // [8][96]
    float* PQ = (float*)Bs;
    #pragma unroll
    for (int nt = 0; nt < 3; ++nt) {
        float s = 0.f, q = 0.f;
        #pragma unroll
        for (int mt = 0; mt < 4; ++mt)
            #pragma unroll
            for (int r = 0; r < 4; ++r) {
                float v = acc[mt][nt][r];
                s += v;
                q = fmaf(v, v, q);
            }
        PS[(wy * 4 + quad) * 96 + wx * 48 + nt * 16 + l16] = s;
        PQ[(wy * 4 + quad) * 96 + wx * 48 + nt * 16 + l16] = q;
    }
    __syncthreads();
    if (tid < 96) {
        float s = 0.f, q = 0.f;
        #pragma unroll
        for (int i = 0; i < 8; ++i) { s += PS[i * 96 + tid]; q += PQ[i * 96 + tid]; }
        psum[blockIdx.y * 1536 + n0 + tid] = s;
        psq [blockIdx.y * 1536 + n0 + tid] = q;
    }
}

// ---------- generic bf16 MFMA GEMM (proj) ----------
template<bool BIAS, int MT, int NT>
__global__ __launch_bounds__(256) void k_gemm_bf16(const short* __restrict__ A,
                                                   const short* __restrict__ B,
                                                   const float* __restrict__ bias,
                                                   float* __restrict__ C,
                                                   int M, int N, int K) {
    constexpr int BM = MT * 32, BN = NT * 32;
    __shared__ __align__(16) short As[BM * 32];
    __shared__ __align__(16) short Bs[BN * 32];
    const int tid  = threadIdx.x;
    const int lane = tid & 63, wv = tid >> 6;
    const int wy = wv >> 1, wx = wv & 1;
    const int quad = lane >> 4, l16 = lane & 15;
    const int m0 = blockIdx.y * BM, n0 = blockIdx.x * BN;

    f32x4 acc[MT][NT];
    #pragma unroll
    for (int i = 0; i < MT; ++i)
        #pragma unroll
        for (int j = 0; j < NT; ++j)
            #pragma unroll
            for (int r = 0; r < 4; ++r) acc[i][j][r] = 0.f;

    constexpr int LA = 2 * MT, LB = 2 * NT;
    const short* gA[(LA + 3) / 4]; short* lA[(LA + 3) / 4]; int nA = 0;
    #pragma unroll
    for (int L0 = 0; L0 < LA; L0 += 4) {
        int L = L0 + wv;
        if (L < LA) {
            int c = L * 64 + lane;
            gA[nA] = A + (size_t)(m0 + (c >> 2)) * K + (c & 3) * 8;
            lA[nA] = &As[L * 512];
            ++nA;
        }
    }
    const short* gB[(LB + 3) / 4]; short* lB[(LB + 3) / 4]; int nB = 0;
    #pragma unroll
    for (int L0 = 0; L0 < LB; L0 += 4) {
        int L = L0 + wv;
        if (L < LB) {
            int c = L * 64 + lane;
            gB[nB] = B + (size_t)(n0 + (c >> 2)) * K + (c & 3) * 8;
            lB[nB] = &Bs[L * 512];
            ++nB;
        }
    }

    for (int k0 = 0; k0 < K; k0 += 32) {
        __syncthreads();
        for (int i = 0; i < nA; ++i) GLOAD_LDS16(gA[i] + k0, lA[i]);
        for (int i = 0; i < nB; ++i) GLOAD_LDS16(gB[i] + k0, lB[i]);
        __syncthreads();
        short8 aF[MT], bF[NT];
        #pragma unroll
        for (int mt = 0; mt < MT; ++mt)
            aF[mt] = *(const short8*)&As[(wy * MT * 16 + mt * 16 + l16) * 32 + quad * 8];
        #pragma unroll
        for (int nt = 0; nt < NT; ++nt)
            bF[nt] = *(const short8*)&Bs[(wx * NT * 16 + nt * 16 + l16) * 32 + quad * 8];
        #pragma unroll
        for (int mt = 0; mt < MT; ++mt)
            #pragma unroll
            for (int nt = 0; nt < NT; ++nt)
                acc[mt][nt] = __builtin_amdgcn_mfma_f32_16x16x32_bf16(aF[mt], bF[nt], acc[mt][nt], 0, 0, 0);
    }

    float bs[NT];
    #pragma unroll
    for (int nt = 0; nt < NT; ++nt) bs[nt] = BIAS ? bias[n0 + wx * NT * 16 + nt * 16 + l16] : 0.f;
    #pragma unroll
    for (int mt = 0; mt < MT; ++mt)
        #pragma unroll
        for (int r = 0; r < 4; ++r) {
            int row = m0 + wy * MT * 16 + mt * 16 + quad * 4 + r;
            float* Cr = C + (size_t)row * N + n0 + wx * NT * 16 + l16;
            #pragma unroll
            for (int nt = 0; nt < NT; ++nt) Cr[nt * 16] = acc[mt][nt][r] + bs[nt];
        }
}

// ---------- BN finalize + spike + pack to i8 q/k (row-major) and v (transposed) ----------
// qkv intermediate is bf16 now.
__global__ __launch_bounds__(256) void k_bn_spike(const short* __restrict__ qkvb,
                           const float* __restrict__ psum, const float* __restrict__ psq,
                           const float* __restrict__ gamma, const float* __restrict__ beta,
                           unsigned char* __restrict__ qp, unsigned char* __restrict__ kp,
                           unsigned char* __restrict__ vt) {
    __shared__ float sa[64], sb[64];
    __shared__ __align__(16) unsigned char tile[64 * 80];
    const int tid = threadIdx.x;
    const int slice = blockIdx.x;            // 0..23
    const int c0 = slice * 64;
    const int r0 = blockIdx.y * 256;
    const int b = r0 >> 10, nb = r0 & 1023;

    if (tid < 64) {
        const int c = c0 + tid;
        double s = 0.0, q = 0.0;
        for (int st = 0; st < 32; ++st) { s += (double)psum[st * 1536 + c]; q += (double)psq[st * 1536 + c]; }
        const double mu  = s / 4096.0;
        const double var = q / 4096.0 - mu * mu;
        const float a = (float)((double)gamma[c] / sqrt(var + 1e-5));
        sa[tid] = a;
        sb[tid] = fmaf(-(float)mu, a, beta[c]);
    }
    __syncthreads();

    const int ch = tid & 63, rq = tid >> 6;
    const float A = sa[ch], Bsh = sb[ch];

    if (slice < 16) {
        const int h = slice & 7;
        unsigned char* base = (slice < 8 ? qp : kp) + (((size_t)b * 8 + h) * 1024 + nb) * 64;
        for (int i = rq; i < 256; i += 4) {
            float v = bf2f((unsigned short)qkvb[(size_t)(r0 + i) * 1536 + c0 + ch]);
            base[(size_t)i * 64 + ch] = (unsigned char)spikef(fmaf(v, A, Bsh));
        }
    } else {
        const int h = slice - 16;
        const int e = tid >> 2, j0 = (tid & 3) * 16;
        unsigned char* vbase = vt + (((size_t)b * 8 + h) * 64 + e) * 1024 + nb;
        for (int rb = 0; rb < 4; ++rb) {
            __syncthreads();
            for (int i = rq; i < 64; i += 4) {
                float v = bf2f((unsigned short)qkvb[(size_t)(r0 + rb * 64 + i) * 1536 + c0 + ch]);
                tile[ch * 80 + i] = (unsigned char)spikef(fmaf(v, A, Bsh));
            }
            __syncthreads();
            *(u32x4*)&vbase[rb * 64 + j0] = *(const u32x4*)&tile[e * 80 + j0];
        }
    }
}

// ---------- fused i8-MFMA attention, 256-wide j-tiles, glds + XOR-swizzled LDS ----------
// Qs/Ks: 64B rows, phys chunk p holds g = p ^ (r&3) ^ ((r>>2)&3).
// Vs: 256B rows (16 chunks), p holds g = p ^ (r&15).
// Sb: 64 rows x 68 dwords (stride ≡ 4 mod 32: write 2-way, b128 reads phase-balanced).
__global__ __launch_bounds__(256) void k_attn(const unsigned char* __restrict__ qp,
                                              const unsigned char* __restrict__ kp,
                                              const unsigned char* __restrict__ vt,
                                              short* __restrict__ sout) {
    __shared__ __align__(16) unsigned char SM[54272];
    unsigned char* Qs = SM;                        // 64 x 64B
    unsigned char* Ks = SM + 4096;                 // 256 x 64B
    unsigned char* Vs = SM + 20480;                // 64 x 256B
    unsigned int* Sb = (unsigned int*)(SM + 36864);// 64 x 68 dw
    const int tid  = threadIdx.x;
    const int lane = tid & 63, w = tid >> 6;
    const int quad = lane >> 4, l16 = lane & 15;
    const int b = blockIdx.z, h = blockIdx.y;
    const int n0 = blockIdx.x * 64;
    const size_t bh = (size_t)b * 8 + h;

    // stage Q via glds (256 chunks, 1/thread)
    {
        const int r = tid >> 2, p = tid & 3;
        const int g = p ^ (r & 3) ^ ((r >> 2) & 3);
        GLOAD_LDS16(qp + (bh * 1024 + n0 + r) * 64 + g * 16, Qs + (size_t)tid * 16);
    }
    // K/V staging pointers: 4 chunks each per thread per 256-row tile
    const unsigned char* gK[4]; unsigned char* lK[4];
    const unsigned char* gV[4]; unsigned char* lV[4];
    #pragma unroll
    for (int i = 0; i < 4; ++i) {
        int c = tid + 256 * i;
        int rk = c >> 2, pk2 = c & 3;
        int gk = pk2 ^ (rk & 3) ^ ((rk >> 2) & 3);
        gK[i] = kp + (bh * 1024 + rk) * 64 + gk * 16;
        lK[i] = Ks + (size_t)c * 16;
        int rv = c >> 4, pv = c & 15;
        int gv = pv ^ (rv & 15);
        gV[i] = vt + (bh * 64 + rv) * 1024 + gv * 16;
        lV[i] = Vs + (size_t)c * 16;
    }
    __syncthreads();
    u32x4 qf[4];
    {
        const int pq = quad ^ (l16 & 3) ^ ((l16 >> 2) & 3);
        #pragma unroll
        for (int mt = 0; mt < 4; ++mt)
            qf[mt] = *(const u32x4*)&Qs[(mt * 16 + l16) * 64 + pq * 16];
    }

    int4v of[4];
    #pragma unroll
    for (int mt = 0; mt < 4; ++mt)
        #pragma unroll
        for (int r = 0; r < 4; ++r) of[mt][r] = 0;

    const int pk = quad ^ (l16 & 3) ^ ((l16 >> 2) & 3);   // K frag phys chunk

    for (int j0 = 0; j0 < 1024; j0 += 256) {
        __syncthreads();
        #pragma unroll
        for (int i = 0; i < 4; ++i) {
            GLOAD_LDS16(gK[i] + (size_t)j0 * 64, lK[i]);
            GLOAD_LDS16(gV[i] + j0, lV[i]);
        }
        __syncthreads();

        // S^T = K Q^T (this wave's 64 j-rows), integer spike clamp, pack -> Sb
        #pragma unroll
        for (int jt = 0; jt < 4; ++jt) {
            u32x4 kf = *(const u32x4*)&Ks[(w * 64 + jt * 16 + l16) * 64 + pk * 16];
            #pragma unroll
            for (int mt = 0; mt < 4; ++mt) {
                int4v z;
                #pragma unroll
                for (int r = 0; r < 4; ++r) z[r] = 0;
                int4v s = mfma_i8(kf, qf[mt], z);
                unsigned int pkk = 0;
                #pragma unroll
                for (int r = 0; r < 4; ++r) {
                    int v = s[r]; v = v < 0 ? 0 : (v > 4 ? 4 : v);
                    pkk |= (unsigned int)v << (8 * r);
                }
                Sb[(mt * 16 + l16) * 68 + w * 16 + jt * 4 + quad] = pkk;
            }
        }
        __syncthreads();

        // PV: out[m][e-slice w] += S~[m][0:256] V[0:256][e]
        #pragma unroll
        for (int kk = 0; kk < 4; ++kk) {
            const int pv = (kk * 4 + quad) ^ l16;
            u32x4 bV = *(const u32x4*)&Vs[(w * 16 + l16) * 256 + pv * 16];
            #pragma unroll
            for (int mt = 0; mt < 4; ++mt) {
                u32x4 aS = *(const u32x4*)&Sb[(mt * 16 + l16) * 68 + kk * 16 + quad * 4];
                of[mt] = mfma_i8(aS, bV, of[mt]);
            }
        }
    }

    // epilogue: spike(out/8) -> bf16 sout (each wave owns its e-slice; no reduce)
    #pragma unroll
    for (int mt = 0; mt < 4; ++mt)
        #pragma unroll
        for (int r = 0; r < 4; ++r) {
            size_t orow = (size_t)b * 1024 + n0 + mt * 16 + quad * 4 + r;
            sout[orow * 512 + h * 64 + w * 16 + l16] =
                (short)f2bf(spikef((float)of[mt][r] * 0.125f));
        }
}

extern "C" void kernel_launch(void* const* d_in, const int* in_sizes, int n_in,
                              void* d_out, int out_size, void* d_ws, size_t ws_size,
                              hipStream_t stream) {
    const float* x     = (const float*)d_in[0];
    const float* Wqkv  = (const float*)d_in[1];
    const float* gamma = (const float*)d_in[2];
    const float* beta  = (const float*)d_in[3];
    const float* Wproj = (const float*)d_in[4];
    const float* bproj = (const float*)d_in[5];
    float* out = (float*)d_out;

    char* w = (char*)d_ws;
    short* xs            = (short*)(w);                     // 4 MB; reused as sout
    short* Wqkv2         = (short*)(w + 8388608);           // 1.5 MB (hi only)
    short* Wproj2        = (short*)(w + 11534336);          // 0.5 MB
    short* qkvb          = (short*)(w + 12582912);          // 12 MB (bf16)
    unsigned char* qp    = (unsigned char*)(w + 37748736);  // 2 MB
    unsigned char* kp    = (unsigned char*)(w + 41943040);  // 2 MB
    unsigned char* vt    = (unsigned char*)(w + 46137344);  // 2 MB
    float* psum          = (float*)(w + 50331648);
    float* psq           = psum + 32 * 1536;
    short* sout          = xs;                              // xs dead after qkv GEMM

    k_prep<<<12288, 256, 0, stream>>>(x, Wqkv, Wproj, xs, Wqkv2, Wproj2);
    k_gemm_qkv<<<dim3(16, 32), 256, 0, stream>>>(xs, Wqkv2, qkvb, psum, psq);
    k_bn_spike<<<dim3(24, 16), 256, 0, stream>>>(qkvb, psum, psq, gamma, beta, qp, kp, vt);
    k_attn<<<dim3(16, 8, 4), 256, 0, stream>>>(qp, kp, vt, sout);
    k_gemm_bf16<true, 1, 4><<<dim3(4, 128), 256, 0, stream>>>(
        sout, Wproj2, bproj, out, 4096, 512, 512);
}